// Round 1
// baseline (856.096 us; speedup 1.0000x reference)
//
#include <hip/hip_runtime.h>
#include <hip/hip_bf16.h>
#include <math.h>

#define N_NODES 10000
#define N_EDGES 160000
#define E_TOT   (N_EDGES + N_NODES)
#define F_IN    300
#define D       1024
#define N_CLS   10
#define NEG_SLOPE 0.2f

// ---------------- CSR build ----------------

__global__ void init_deg(int* __restrict__ deg) {
    int i = blockIdx.x * blockDim.x + threadIdx.x;
    if (i < N_NODES) deg[i] = 1;  // self loop contributes 1
}

__global__ void count_edges(const int* __restrict__ dst, int* __restrict__ deg) {
    int e = blockIdx.x * blockDim.x + threadIdx.x;
    if (e < N_EDGES) atomicAdd(&deg[dst[e]], 1);
}

// single-block chunked Hillis-Steele scan over 10000 degrees
__global__ void scan_offs(const int* __restrict__ deg, int* __restrict__ offs,
                          int* __restrict__ pos) {
    __shared__ int sbuf[1024];
    __shared__ int scarry;
    int t = threadIdx.x;
    if (t == 0) { scarry = 0; offs[0] = 0; }
    __syncthreads();
    for (int base = 0; base < N_NODES; base += 1024) {
        int v = (base + t < N_NODES) ? deg[base + t] : 0;
        sbuf[t] = v;
        __syncthreads();
        for (int off = 1; off < 1024; off <<= 1) {
            int add = (t >= off) ? sbuf[t - off] : 0;
            __syncthreads();
            sbuf[t] += add;
            __syncthreads();
        }
        int carry = scarry;
        if (base + t < N_NODES) {
            int incl = carry + sbuf[t];
            offs[base + t + 1] = incl;
            pos[base + t]      = incl - v;  // exclusive prefix = segment start
        }
        __syncthreads();
        if (t == 1023) scarry = carry + sbuf[1023];
        __syncthreads();
    }
}

__global__ void scatter_edges(const int* __restrict__ src, const int* __restrict__ dst,
                              int* __restrict__ pos, int* __restrict__ ssrc) {
    int e = blockIdx.x * blockDim.x + threadIdx.x;
    if (e < N_EDGES) {
        int d = dst[e];
        int p = atomicAdd(&pos[d], 1);
        ssrc[p] = src[e];
    } else if (e < E_TOT) {
        int i = e - N_EDGES;
        int p = atomicAdd(&pos[i], 1);
        ssrc[p] = i;
    }
}

// ---------------- fp32 tiled GEMM: C[M,N] = A[M,K] * B[K,N] ----------------
// 64x64 tile, 256 threads, 4x4 micro-tile, BK=16

__global__ __launch_bounds__(256) void gemm64(const float* __restrict__ A,
                                              const float* __restrict__ B,
                                              float* __restrict__ C,
                                              int M, int K, int N) {
    __shared__ float As[16][68];   // padded +4 -> 2-way max on write
    __shared__ float Bs[16][64];
    int tx = threadIdx.x & 15;     // col group
    int ty = threadIdx.x >> 4;     // row group
    int n0 = blockIdx.x * 64;
    int m0 = blockIdx.y * 64;
    float acc[4][4] = {};

    for (int k0 = 0; k0 < K; k0 += 16) {
        #pragma unroll
        for (int i = 0; i < 4; ++i) {
            int idx = (int)threadIdx.x + i * 256;
            int r = idx >> 4, kk = idx & 15;
            int m = m0 + r, k = k0 + kk;
            As[kk][r] = (m < M && k < K) ? A[(size_t)m * K + k] : 0.f;
        }
        {
            int r = threadIdx.x >> 4;  // 0..15
            int k = k0 + r;
            float4 bv = {0.f, 0.f, 0.f, 0.f};
            if (k < K) bv = *(const float4*)(B + (size_t)k * N + n0 + tx * 4);
            *(float4*)&Bs[r][tx * 4] = bv;
        }
        __syncthreads();
        #pragma unroll
        for (int kk = 0; kk < 16; ++kk) {
            float a0 = As[kk][ty * 4 + 0];
            float a1 = As[kk][ty * 4 + 1];
            float a2 = As[kk][ty * 4 + 2];
            float a3 = As[kk][ty * 4 + 3];
            float4 b4 = *(const float4*)&Bs[kk][tx * 4];
            acc[0][0] += a0 * b4.x; acc[0][1] += a0 * b4.y; acc[0][2] += a0 * b4.z; acc[0][3] += a0 * b4.w;
            acc[1][0] += a1 * b4.x; acc[1][1] += a1 * b4.y; acc[1][2] += a1 * b4.z; acc[1][3] += a1 * b4.w;
            acc[2][0] += a2 * b4.x; acc[2][1] += a2 * b4.y; acc[2][2] += a2 * b4.z; acc[2][3] += a2 * b4.w;
            acc[3][0] += a3 * b4.x; acc[3][1] += a3 * b4.y; acc[3][2] += a3 * b4.z; acc[3][3] += a3 * b4.w;
        }
        __syncthreads();
    }
    #pragma unroll
    for (int i = 0; i < 4; ++i) {
        int m = m0 + ty * 4 + i;
        if (m < M) {
            float4 v = {acc[i][0], acc[i][1], acc[i][2], acc[i][3]};
            *(float4*)(C + (size_t)m * N + n0 + tx * 4) = v;
        }
    }
}

// ---------------- per-node attention dots: hs=h.a_src, hd=h.a_dst ----------------

__global__ void node_dots(const float* __restrict__ h, const float* __restrict__ asrc,
                          const float* __restrict__ adst, float* __restrict__ hs,
                          float* __restrict__ hd) {
    int wid  = (int)((blockIdx.x * blockDim.x + threadIdx.x) >> 6);
    int lane = threadIdx.x & 63;
    if (wid >= N_NODES) return;
    const float* row = h + (size_t)wid * D;
    float s1 = 0.f, s2 = 0.f;
    for (int k = lane; k < D; k += 64) {
        float v = row[k];
        s1 += v * asrc[k];
        s2 += v * adst[k];
    }
    #pragma unroll
    for (int o = 32; o; o >>= 1) {
        s1 += __shfl_xor(s1, o);
        s2 += __shfl_xor(s2, o);
    }
    if (lane == 0) { hs[wid] = s1; hd[wid] = s2; }
}

// ---------------- per-dst softmax + weighted aggregation ----------------
// one block (256 threads) per destination node

__global__ __launch_bounds__(256) void gat_aggregate(
        const float* __restrict__ h, const float* __restrict__ hs,
        const float* __restrict__ hd, const int* __restrict__ offs,
        const int* __restrict__ ssrc, float* __restrict__ sscore,
        const float* __restrict__ bias, float* __restrict__ out, int applyRelu) {
    int i = blockIdx.x;
    int t = threadIdx.x;
    int lane = t & 63;
    int start = offs[i], end = offs[i + 1];
    __shared__ float s_inv_denom;

    if (t < 64) {  // wave 0: softmax over the segment
        float hdi  = hd[i];
        float lmax = -INFINITY;
        for (int p = start + lane; p < end; p += 64) {
            float s = hs[ssrc[p]] + hdi;
            s = (s >= 0.f) ? s : s * NEG_SLOPE;  // leaky_relu
            sscore[p] = s;
            lmax = fmaxf(lmax, s);
        }
        #pragma unroll
        for (int o = 32; o; o >>= 1) lmax = fmaxf(lmax, __shfl_xor(lmax, o));
        float lsum = 0.f;
        for (int p = start + lane; p < end; p += 64) {
            float ex = __expf(sscore[p] - lmax);
            sscore[p] = ex;           // store unnormalized weight
            lsum += ex;
        }
        #pragma unroll
        for (int o = 32; o; o >>= 1) lsum += __shfl_xor(lsum, o);
        if (lane == 0) s_inv_denom = 1.0f / lsum;
    }
    __syncthreads();
    float inv = s_inv_denom;

    // all 256 threads: 4 contiguous cols each (float4)
    int c = t * 4;
    float4 acc = {0.f, 0.f, 0.f, 0.f};
    for (int p = start; p < end; ++p) {
        float a  = sscore[p];                     // broadcast
        int   sj = ssrc[p];                       // broadcast
        float4 hv = *(const float4*)(h + (size_t)sj * D + c);
        acc.x += a * hv.x; acc.y += a * hv.y; acc.z += a * hv.z; acc.w += a * hv.w;
    }
    float4 b4 = *(const float4*)(bias + c);
    float4 r;
    r.x = acc.x * inv + b4.x;
    r.y = acc.y * inv + b4.y;
    r.z = acc.z * inv + b4.z;
    r.w = acc.w * inv + b4.w;
    if (applyRelu) {
        r.x = fmaxf(r.x, 0.f); r.y = fmaxf(r.y, 0.f);
        r.z = fmaxf(r.z, 0.f); r.w = fmaxf(r.w, 0.f);
    }
    *(float4*)(out + (size_t)i * D + c) = r;
}

// ---------------- final fc + softmax, one wave per node ----------------

__global__ void fc_softmax(const float* __restrict__ emb, const float* __restrict__ fcw,
                           const float* __restrict__ fcb, float* __restrict__ out) {
    int wid  = (int)((blockIdx.x * blockDim.x + threadIdx.x) >> 6);
    int lane = threadIdx.x & 63;
    if (wid >= N_NODES) return;
    float acc[N_CLS] = {};
    const float* row = emb + (size_t)wid * D;
    for (int k = lane; k < D; k += 64) {
        float v = row[k];
        #pragma unroll
        for (int c = 0; c < N_CLS; ++c) acc[c] += v * fcw[k * N_CLS + c];
    }
    #pragma unroll
    for (int c = 0; c < N_CLS; ++c) {
        #pragma unroll
        for (int o = 32; o; o >>= 1) acc[c] += __shfl_xor(acc[c], o);
    }
    if (lane == 0) {
        float logit[N_CLS];
        float m = -INFINITY;
        #pragma unroll
        for (int c = 0; c < N_CLS; ++c) { logit[c] = acc[c] + fcb[c]; m = fmaxf(m, logit[c]); }
        float s = 0.f;
        #pragma unroll
        for (int c = 0; c < N_CLS; ++c) { logit[c] = __expf(logit[c] - m); s += logit[c]; }
        float invs = 1.0f / s;
        #pragma unroll
        for (int c = 0; c < N_CLS; ++c) out[(size_t)wid * N_CLS + c] = logit[c] * invs;
    }
}

// ---------------- launch ----------------

extern "C" void kernel_launch(void* const* d_in, const int* in_sizes, int n_in,
                              void* d_out, int out_size, void* d_ws, size_t ws_size,
                              hipStream_t stream) {
    const float* x        = (const float*)d_in[0];
    const int*   ei       = (const int*)d_in[1];      // [2, E] flat: src then dst
    const float* W1       = (const float*)d_in[2];
    const float* att_src1 = (const float*)d_in[3];
    const float* att_dst1 = (const float*)d_in[4];
    const float* b1       = (const float*)d_in[5];
    const float* W2       = (const float*)d_in[6];
    const float* att_src2 = (const float*)d_in[7];
    const float* att_dst2 = (const float*)d_in[8];
    const float* b2       = (const float*)d_in[9];
    const float* fc_w     = (const float*)d_in[10];
    const float* fc_b     = (const float*)d_in[11];
    float* out = (float*)d_out;

    const int* src = ei;
    const int* dst = ei + N_EDGES;

    char* w = (char*)d_ws;
    float* h      = (float*)w;  w += (size_t)N_NODES * D * 4;
    float* emb    = (float*)w;  w += (size_t)N_NODES * D * 4;
    float* sscore = (float*)w;  w += (size_t)E_TOT * 4;
    float* hs     = (float*)w;  w += (size_t)N_NODES * 4;
    float* hd     = (float*)w;  w += (size_t)N_NODES * 4;
    int*   deg    = (int*)w;    w += (size_t)N_NODES * 4;
    int*   offs   = (int*)w;    w += (size_t)(N_NODES + 1) * 4;
    int*   pos    = (int*)w;    w += (size_t)N_NODES * 4;
    int*   ssrc   = (int*)w;    w += (size_t)E_TOT * 4;

    // CSR build
    init_deg<<<(N_NODES + 255) / 256, 256, 0, stream>>>(deg);
    count_edges<<<(N_EDGES + 255) / 256, 256, 0, stream>>>(dst, deg);
    scan_offs<<<1, 1024, 0, stream>>>(deg, offs, pos);
    scatter_edges<<<(E_TOT + 255) / 256, 256, 0, stream>>>(src, dst, pos, ssrc);

    dim3 gemmGrid(D / 64, (N_NODES + 63) / 64);

    // layer 1
    gemm64<<<gemmGrid, 256, 0, stream>>>(x, W1, h, N_NODES, F_IN, D);
    node_dots<<<(N_NODES * 64 + 255) / 256, 256, 0, stream>>>(h, att_src1, att_dst1, hs, hd);
    gat_aggregate<<<N_NODES, 256, 0, stream>>>(h, hs, hd, offs, ssrc, sscore, b1, emb, 1);

    // layer 2
    gemm64<<<gemmGrid, 256, 0, stream>>>(emb, W2, h, N_NODES, D, D);
    node_dots<<<(N_NODES * 64 + 255) / 256, 256, 0, stream>>>(h, att_src2, att_dst2, hs, hd);
    gat_aggregate<<<N_NODES, 256, 0, stream>>>(h, hs, hd, offs, ssrc, sscore, b2, emb, 1);

    // classifier
    fc_softmax<<<(N_NODES * 64 + 255) / 256, 256, 0, stream>>>(emb, fc_w, fc_b, out);
}

// Round 3
// 567.264 us; speedup vs baseline: 1.5092x; 1.5092x over previous
//
#include <hip/hip_runtime.h>
#include <hip/hip_bf16.h>
#include <math.h>

#define N_NODES 10000
#define N_EDGES 160000
#define E_TOT   (N_EDGES + N_NODES)
#define F_IN    300
#define D       1024
#define N_CLS   10
#define NEG_SLOPE 0.2f

#define MP      10112              // 79 * 128, padded M
#define KP1     320                // F_IN padded to mult of 64
#define KP2     1024

typedef __attribute__((ext_vector_type(8))) short bf16x8;
typedef __attribute__((ext_vector_type(4))) float f32x4;

#define GLOAD_LDS16(g, l) __builtin_amdgcn_global_load_lds( \
    (const __attribute__((address_space(1))) void*)(g), \
    (__attribute__((address_space(3))) void*)(l), 16, 0, 0)

// ---------------- CSR build ----------------

__global__ void init_deg(int* __restrict__ deg) {
    int i = blockIdx.x * blockDim.x + threadIdx.x;
    if (i < N_NODES) deg[i] = 1;  // self loop contributes 1
}

__global__ void count_edges(const int* __restrict__ dst, int* __restrict__ deg) {
    int e = blockIdx.x * blockDim.x + threadIdx.x;
    if (e < N_EDGES) atomicAdd(&deg[dst[e]], 1);
}

__global__ void scan_offs(const int* __restrict__ deg, int* __restrict__ offs,
                          int* __restrict__ pos) {
    __shared__ int sbuf[1024];
    __shared__ int scarry;
    int t = threadIdx.x;
    if (t == 0) { scarry = 0; offs[0] = 0; }
    __syncthreads();
    for (int base = 0; base < N_NODES; base += 1024) {
        int v = (base + t < N_NODES) ? deg[base + t] : 0;
        sbuf[t] = v;
        __syncthreads();
        for (int off = 1; off < 1024; off <<= 1) {
            int add = (t >= off) ? sbuf[t - off] : 0;
            __syncthreads();
            sbuf[t] += add;
            __syncthreads();
        }
        int carry = scarry;
        if (base + t < N_NODES) {
            int incl = carry + sbuf[t];
            offs[base + t + 1] = incl;
            pos[base + t]      = incl - v;
        }
        __syncthreads();
        if (t == 1023) scarry = carry + sbuf[1023];
        __syncthreads();
    }
}

__global__ void scatter_edges(const int* __restrict__ src, const int* __restrict__ dst,
                              int* __restrict__ pos, int* __restrict__ ssrc) {
    int e = blockIdx.x * blockDim.x + threadIdx.x;
    if (e < N_EDGES) {
        int d = dst[e];
        int p = atomicAdd(&pos[d], 1);
        ssrc[p] = src[e];
    } else if (e < E_TOT) {
        int i = e - N_EDGES;
        int p = atomicAdd(&pos[i], 1);
        ssrc[p] = i;
    }
}

// ---------------- hi/lo bf16 split of row-major A [M][K] -> [Mp][Kp] ----------------

__global__ void split_rows(const float* __restrict__ A, __hip_bfloat16* __restrict__ Ah,
                           __hip_bfloat16* __restrict__ Al, int M, int K, int Mp, int Kp) {
    int idx = blockIdx.x * blockDim.x + threadIdx.x;
    if (idx >= Mp * Kp) return;
    int m = idx / Kp, k = idx - m * Kp;
    float v = (m < M && k < K) ? A[(size_t)m * K + k] : 0.f;
    __hip_bfloat16 hi = __float2bfloat16(v);
    float r = v - __bfloat162float(hi);
    Ah[idx] = hi;
    Al[idx] = __float2bfloat16(r);
}

// ---------------- transpose + hi/lo split of W [K][N] -> BT [N][Kp] ----------------

__global__ void transpose_split(const float* __restrict__ W, __hip_bfloat16* __restrict__ BTh,
                                __hip_bfloat16* __restrict__ BTl, int K, int N, int Kp) {
    __shared__ float tile[32][33];
    int k0 = blockIdx.x * 32, n0 = blockIdx.y * 32;
    int tx = threadIdx.x, ty = threadIdx.y;
    #pragma unroll
    for (int j = 0; j < 32; j += 8) {
        int k = k0 + ty + j;
        tile[ty + j][tx] = (k < K) ? W[(size_t)k * N + n0 + tx] : 0.f;
    }
    __syncthreads();
    #pragma unroll
    for (int j = 0; j < 32; j += 8) {
        int n = n0 + ty + j;
        int k = k0 + tx;
        float v = tile[tx][ty + j];
        __hip_bfloat16 hi = __float2bfloat16(v);
        float r = v - __bfloat162float(hi);
        BTh[(size_t)n * Kp + k] = hi;
        BTl[(size_t)n * Kp + k] = __float2bfloat16(r);
    }
}

// ---------------- split-bf16 MFMA GEMM ----------------
// C[M][1024] = (Ah+Al) @ (BTh+BTl)^T via expanded K: [Ah|Al|Ah] x [BTh|BTh|BTl]
// 128x128 tile, 4 waves, 4x4 frags of mfma_f32_16x16x32_bf16, BK=64.
// LDS: linear dest for global_load_lds; XOR swizzle (row&7)<<4 applied to the
// GLOBAL source address on staging and to the ds_read byte offset (rule #21).

__global__ __launch_bounds__(256) void gemm_split_mfma(
        const __hip_bfloat16* __restrict__ Ah, const __hip_bfloat16* __restrict__ Al,
        const __hip_bfloat16* __restrict__ BTh, const __hip_bfloat16* __restrict__ BTl,
        float* __restrict__ C, int Mreal, int Kp) {
    __shared__ char As[128 * 128];   // 128 rows x 64 bf16 (128B per row)
    __shared__ char Bs[128 * 128];
    const int t    = threadIdx.x;
    const int lane = t & 63;
    const int wid  = t >> 6;
    const int m0 = blockIdx.y * 128;
    const int n0 = blockIdx.x * 128;
    const int wr = (wid >> 1) * 64;
    const int wc = (wid & 1) * 64;
    const int fr = lane & 15;        // frag row (m or n) within 16
    const int kg = lane >> 4;        // k-group 0..3
    const int swz = (fr & 7) << 4;   // read-side swizzle (row&7 == fr&7 for all frags)
    const int Keff = 3 * Kp;

    // staging geometry: chunk = i*256 + t; LDS dest byte = chunk*16 (linear)
    const int rbase = t >> 3;                                   // row within 32-row group
    const int srcb  = ((t & 7) << 4) ^ (((t >> 3) & 7) << 4);   // pre-swizzled src byte
    const int scol  = srcb >> 1;                                // src element offset in [0,64)

    f32x4 acc[4][4] = {};

    for (int k0 = 0; k0 < Keff; k0 += 64) {
        const int seg = (k0 >= Kp) + (k0 >= 2 * Kp);   // 0,1,2
        const int kb  = k0 - seg * Kp;
        const __hip_bfloat16* SA = (seg == 1) ? Al  : Ah;
        const __hip_bfloat16* SB = (seg == 2) ? BTl : BTh;
        #pragma unroll
        for (int i = 0; i < 4; ++i) {
            int row = i * 32 + rbase;
            const __hip_bfloat16* ga = SA + (size_t)(m0 + row) * Kp + kb + scol;
            const __hip_bfloat16* gb = SB + (size_t)(n0 + row) * Kp + kb + scol;
            GLOAD_LDS16(ga, As + (i * 256 + wid * 64) * 16);
            GLOAD_LDS16(gb, Bs + (i * 256 + wid * 64) * 16);
        }
        __syncthreads();
        #pragma unroll
        for (int kk = 0; kk < 2; ++kk) {
            const int ko = (kk * 64 + kg * 16) ^ swz;
            bf16x8 af[4], bfr[4];
            #pragma unroll
            for (int f = 0; f < 4; ++f) {
                af[f]  = *(const bf16x8*)(As + (wr + f * 16 + fr) * 128 + ko);
                bfr[f] = *(const bf16x8*)(Bs + (wc + f * 16 + fr) * 128 + ko);
            }
            #pragma unroll
            for (int fm = 0; fm < 4; ++fm)
                #pragma unroll
                for (int fn = 0; fn < 4; ++fn)
                    acc[fm][fn] = __builtin_amdgcn_mfma_f32_16x16x32_bf16(
                        af[fm], bfr[fn], acc[fm][fn], 0, 0, 0);
        }
        __syncthreads();
    }

    // epilogue: C/D layout col=lane&15, row=(lane>>4)*4+j
    #pragma unroll
    for (int fm = 0; fm < 4; ++fm) {
        int mb = m0 + wr + fm * 16 + kg * 4;
        #pragma unroll
        for (int fn = 0; fn < 4; ++fn) {
            int cn = n0 + wc + fn * 16 + fr;
            #pragma unroll
            for (int j = 0; j < 4; ++j) {
                int m = mb + j;
                if (m < Mreal) C[(size_t)m * 1024 + cn] = acc[fm][fn][j];
            }
        }
    }
}

// ---------------- per-node attention dots ----------------

__global__ void node_dots(const float* __restrict__ h, const float* __restrict__ asrc,
                          const float* __restrict__ adst, float* __restrict__ hs,
                          float* __restrict__ hd) {
    int wid  = (int)((blockIdx.x * blockDim.x + threadIdx.x) >> 6);
    int lane = threadIdx.x & 63;
    if (wid >= N_NODES) return;
    const float* row = h + (size_t)wid * D;
    float s1 = 0.f, s2 = 0.f;
    for (int k = lane; k < D; k += 64) {
        float v = row[k];
        s1 += v * asrc[k];
        s2 += v * adst[k];
    }
    #pragma unroll
    for (int o = 32; o; o >>= 1) {
        s1 += __shfl_xor(s1, o);
        s2 += __shfl_xor(s2, o);
    }
    if (lane == 0) { hs[wid] = s1; hd[wid] = s2; }
}

// ---------------- per-dst softmax + weighted aggregation ----------------

__global__ __launch_bounds__(256) void gat_aggregate(
        const float* __restrict__ h, const float* __restrict__ hs,
        const float* __restrict__ hd, const int* __restrict__ offs,
        const int* __restrict__ ssrc, float* __restrict__ sscore,
        const float* __restrict__ bias, float* __restrict__ out, int applyRelu) {
    int i = blockIdx.x;
    int t = threadIdx.x;
    int lane = t & 63;
    int start = offs[i], end = offs[i + 1];
    __shared__ float s_inv_denom;

    if (t < 64) {
        float hdi  = hd[i];
        float lmax = -INFINITY;
        for (int p = start + lane; p < end; p += 64) {
            float s = hs[ssrc[p]] + hdi;
            s = (s >= 0.f) ? s : s * NEG_SLOPE;
            sscore[p] = s;
            lmax = fmaxf(lmax, s);
        }
        #pragma unroll
        for (int o = 32; o; o >>= 1) lmax = fmaxf(lmax, __shfl_xor(lmax, o));
        float lsum = 0.f;
        for (int p = start + lane; p < end; p += 64) {
            float ex = __expf(sscore[p] - lmax);
            sscore[p] = ex;
            lsum += ex;
        }
        #pragma unroll
        for (int o = 32; o; o >>= 1) lsum += __shfl_xor(lsum, o);
        if (lane == 0) s_inv_denom = 1.0f / lsum;
    }
    __syncthreads();
    float inv = s_inv_denom;

    int c = t * 4;
    float4 acc = {0.f, 0.f, 0.f, 0.f};
    for (int p = start; p < end; ++p) {
        float a  = sscore[p];
        int   sj = ssrc[p];
        float4 hv = *(const float4*)(h + (size_t)sj * D + c);
        acc.x += a * hv.x; acc.y += a * hv.y; acc.z += a * hv.z; acc.w += a * hv.w;
    }
    float4 b4 = *(const float4*)(bias + c);
    float4 r;
    r.x = acc.x * inv + b4.x;
    r.y = acc.y * inv + b4.y;
    r.z = acc.z * inv + b4.z;
    r.w = acc.w * inv + b4.w;
    if (applyRelu) {
        r.x = fmaxf(r.x, 0.f); r.y = fmaxf(r.y, 0.f);
        r.z = fmaxf(r.z, 0.f); r.w = fmaxf(r.w, 0.f);
    }
    *(float4*)(out + (size_t)i * D + c) = r;
}

// ---------------- final fc + softmax ----------------

__global__ void fc_softmax(const float* __restrict__ emb, const float* __restrict__ fcw,
                           const float* __restrict__ fcb, float* __restrict__ out) {
    int wid  = (int)((blockIdx.x * blockDim.x + threadIdx.x) >> 6);
    int lane = threadIdx.x & 63;
    if (wid >= N_NODES) return;
    float acc[N_CLS] = {};
    const float* row = emb + (size_t)wid * D;
    for (int k = lane; k < D; k += 64) {
        float v = row[k];
        #pragma unroll
        for (int c = 0; c < N_CLS; ++c) acc[c] += v * fcw[k * N_CLS + c];
    }
    #pragma unroll
    for (int c = 0; c < N_CLS; ++c) {
        #pragma unroll
        for (int o = 32; o; o >>= 1) acc[c] += __shfl_xor(acc[c], o);
    }
    if (lane == 0) {
        float logit[N_CLS];
        float m = -INFINITY;
        #pragma unroll
        for (int c = 0; c < N_CLS; ++c) { logit[c] = acc[c] + fcb[c]; m = fmaxf(m, logit[c]); }
        float s = 0.f;
        #pragma unroll
        for (int c = 0; c < N_CLS; ++c) { logit[c] = __expf(logit[c] - m); s += logit[c]; }
        float invs = 1.0f / s;
        #pragma unroll
        for (int c = 0; c < N_CLS; ++c) out[(size_t)wid * N_CLS + c] = logit[c] * invs;
    }
}

// ---------------- launch ----------------

extern "C" void kernel_launch(void* const* d_in, const int* in_sizes, int n_in,
                              void* d_out, int out_size, void* d_ws, size_t ws_size,
                              hipStream_t stream) {
    const float* x        = (const float*)d_in[0];
    const int*   ei       = (const int*)d_in[1];
    const float* W1       = (const float*)d_in[2];
    const float* att_src1 = (const float*)d_in[3];
    const float* att_dst1 = (const float*)d_in[4];
    const float* b1       = (const float*)d_in[5];
    const float* W2       = (const float*)d_in[6];
    const float* att_src2 = (const float*)d_in[7];
    const float* att_dst2 = (const float*)d_in[8];
    const float* b2       = (const float*)d_in[9];
    const float* fc_w     = (const float*)d_in[10];
    const float* fc_b     = (const float*)d_in[11];
    float* out = (float*)d_out;

    const int* src = ei;
    const int* dst = ei + N_EDGES;

    char* w = (char*)d_ws;
    #define ALLOC(name, bytes) char* name = w; w += (((size_t)(bytes) + 255) & ~(size_t)255)
    ALLOC(p_h,     (size_t)N_NODES * D * 4);
    ALLOC(p_emb,   (size_t)N_NODES * D * 4);
    ALLOC(p_score, (size_t)E_TOT * 4);
    ALLOC(p_hs,    (size_t)N_NODES * 4);
    ALLOC(p_hd,    (size_t)N_NODES * 4);
    ALLOC(p_deg,   (size_t)N_NODES * 4);
    ALLOC(p_offs,  (size_t)(N_NODES + 1) * 4);
    ALLOC(p_pos,   (size_t)N_NODES * 4);
    ALLOC(p_ssrc,  (size_t)E_TOT * 4);
    // A-split region shared by layer 1 and layer 2 (never live simultaneously)
    ALLOC(p_asplit, (size_t)2 * MP * KP2 * 2);
    ALLOC(p_bt1h,  (size_t)D * KP1 * 2);
    ALLOC(p_bt1l,  (size_t)D * KP1 * 2);
    ALLOC(p_bt2h,  (size_t)D * KP2 * 2);
    ALLOC(p_bt2l,  (size_t)D * KP2 * 2);
    #undef ALLOC

    float* h      = (float*)p_h;
    float* emb    = (float*)p_emb;
    float* sscore = (float*)p_score;
    float* hs     = (float*)p_hs;
    float* hd     = (float*)p_hd;
    int*   deg    = (int*)p_deg;
    int*   offs   = (int*)p_offs;
    int*   pos    = (int*)p_pos;
    int*   ssrc   = (int*)p_ssrc;
    __hip_bfloat16* Ah1  = (__hip_bfloat16*)p_asplit;
    __hip_bfloat16* Al1  = Ah1 + (size_t)MP * KP1;
    __hip_bfloat16* Ah2  = (__hip_bfloat16*)p_asplit;
    __hip_bfloat16* Al2  = Ah2 + (size_t)MP * KP2;
    __hip_bfloat16* BT1h = (__hip_bfloat16*)p_bt1h;
    __hip_bfloat16* BT1l = (__hip_bfloat16*)p_bt1l;
    __hip_bfloat16* BT2h = (__hip_bfloat16*)p_bt2h;
    __hip_bfloat16* BT2l = (__hip_bfloat16*)p_bt2l;

    // CSR build
    init_deg<<<(N_NODES + 255) / 256, 256, 0, stream>>>(deg);
    count_edges<<<(N_EDGES + 255) / 256, 256, 0, stream>>>(dst, deg);
    scan_offs<<<1, 1024, 0, stream>>>(deg, offs, pos);
    scatter_edges<<<(E_TOT + 255) / 256, 256, 0, stream>>>(src, dst, pos, ssrc);

    // weight transpose+split (independent of graph work)
    dim3 tb(32, 8);
    transpose_split<<<dim3(KP1 / 32, D / 32), tb, 0, stream>>>(W1, BT1h, BT1l, F_IN, D, KP1);
    transpose_split<<<dim3(KP2 / 32, D / 32), tb, 0, stream>>>(W2, BT2h, BT2l, D, D, KP2);

    dim3 gemmGrid(D / 128, MP / 128);

    // layer 1: h = x @ W1 (split-bf16 MFMA)
    split_rows<<<((size_t)MP * KP1 + 255) / 256, 256, 0, stream>>>(x, Ah1, Al1, N_NODES, F_IN, MP, KP1);
    gemm_split_mfma<<<gemmGrid, 256, 0, stream>>>(Ah1, Al1, BT1h, BT1l, h, N_NODES, KP1);
    node_dots<<<(N_NODES * 64 + 255) / 256, 256, 0, stream>>>(h, att_src1, att_dst1, hs, hd);
    gat_aggregate<<<N_NODES, 256, 0, stream>>>(h, hs, hd, offs, ssrc, sscore, b1, emb, 1);

    // layer 2: h = emb @ W2
    split_rows<<<((size_t)MP * KP2 + 255) / 256, 256, 0, stream>>>(emb, Ah2, Al2, N_NODES, D, MP, KP2);
    gemm_split_mfma<<<gemmGrid, 256, 0, stream>>>(Ah2, Al2, BT2h, BT2l, h, N_NODES, KP2);
    node_dots<<<(N_NODES * 64 + 255) / 256, 256, 0, stream>>>(h, att_src2, att_dst2, hs, hd);
    gat_aggregate<<<N_NODES, 256, 0, stream>>>(h, hs, hd, offs, ssrc, sscore, b2, emb, 1);

    // classifier
    fc_softmax<<<(N_NODES * 64 + 255) / 256, 256, 0, stream>>>(emb, fc_w, fc_b, out);
}

// Round 4
// 536.364 us; speedup vs baseline: 1.5961x; 1.0576x over previous
//
#include <hip/hip_runtime.h>
#include <hip/hip_bf16.h>
#include <math.h>

#define N_NODES 10000
#define N_EDGES 160000
#define E_TOT   (N_EDGES + N_NODES)
#define F_IN    300
#define D       1024
#define N_CLS   10
#define NEG_SLOPE 0.2f

#define MP      10112              // 79 * 128, padded M
#define KP1     320                // F_IN padded to mult of 64
#define KP2     1024

typedef __attribute__((ext_vector_type(8))) short bf16x8;
typedef __attribute__((ext_vector_type(4))) float f32x4;

#define GLOAD_LDS16(g, l) __builtin_amdgcn_global_load_lds( \
    (const __attribute__((address_space(1))) void*)(g), \
    (__attribute__((address_space(3))) void*)(l), 16, 0, 0)

// ---------------- CSR build ----------------

__global__ void init_deg(int* __restrict__ deg) {
    int i = blockIdx.x * blockDim.x + threadIdx.x;
    if (i < N_NODES) deg[i] = 1;  // self loop contributes 1
}

__global__ void count_edges(const int* __restrict__ dst, int* __restrict__ deg) {
    int e = blockIdx.x * blockDim.x + threadIdx.x;
    if (e < N_EDGES) atomicAdd(&deg[dst[e]], 1);
}

__global__ void scan_offs(const int* __restrict__ deg, int* __restrict__ offs,
                          int* __restrict__ pos) {
    __shared__ int sbuf[1024];
    __shared__ int scarry;
    int t = threadIdx.x;
    if (t == 0) { scarry = 0; offs[0] = 0; }
    __syncthreads();
    for (int base = 0; base < N_NODES; base += 1024) {
        int v = (base + t < N_NODES) ? deg[base + t] : 0;
        sbuf[t] = v;
        __syncthreads();
        for (int off = 1; off < 1024; off <<= 1) {
            int add = (t >= off) ? sbuf[t - off] : 0;
            __syncthreads();
            sbuf[t] += add;
            __syncthreads();
        }
        int carry = scarry;
        if (base + t < N_NODES) {
            int incl = carry + sbuf[t];
            offs[base + t + 1] = incl;
            pos[base + t]      = incl - v;
        }
        __syncthreads();
        if (t == 1023) scarry = carry + sbuf[1023];
        __syncthreads();
    }
}

__global__ void scatter_edges(const int* __restrict__ src, const int* __restrict__ dst,
                              int* __restrict__ pos, int* __restrict__ ssrc) {
    int e = blockIdx.x * blockDim.x + threadIdx.x;
    if (e < N_EDGES) {
        int d = dst[e];
        int p = atomicAdd(&pos[d], 1);
        ssrc[p] = src[e];
    } else if (e < E_TOT) {
        int i = e - N_EDGES;
        int p = atomicAdd(&pos[i], 1);
        ssrc[p] = i;
    }
}

// ---------------- small utility kernels ----------------

__global__ void zero2(float* __restrict__ a, float* __restrict__ b, int n) {
    int i = blockIdx.x * blockDim.x + threadIdx.x;
    if (i < n) { a[i] = 0.f; b[i] = 0.f; }
}

// zero the padded rows [N_NODES, MP) of the layer-2 A-split buffers
__global__ void zero_pad_rows(__hip_bfloat16* __restrict__ Ah, __hip_bfloat16* __restrict__ Al) {
    int idx = blockIdx.x * blockDim.x + threadIdx.x;
    const int total = (MP - N_NODES) * KP2;
    if (idx < total) {
        __hip_bfloat16 z = __float2bfloat16(0.f);
        Ah[(size_t)N_NODES * KP2 + idx] = z;
        Al[(size_t)N_NODES * KP2 + idx] = z;
    }
}

// ---------------- hi/lo bf16 split of row-major A [M][K] -> [Mp][Kp] ----------------

__global__ void split_rows(const float* __restrict__ A, __hip_bfloat16* __restrict__ Ah,
                           __hip_bfloat16* __restrict__ Al, int M, int K, int Mp, int Kp) {
    int idx = blockIdx.x * blockDim.x + threadIdx.x;
    if (idx >= Mp * Kp) return;
    int m = idx / Kp, k = idx - m * Kp;
    float v = (m < M && k < K) ? A[(size_t)m * K + k] : 0.f;
    __hip_bfloat16 hi = __float2bfloat16(v);
    float r = v - __bfloat162float(hi);
    Ah[idx] = hi;
    Al[idx] = __float2bfloat16(r);
}

// ---------------- transpose + hi/lo split of W [K][N] -> BT [N][Kp] ----------------

__global__ void transpose_split(const float* __restrict__ W, __hip_bfloat16* __restrict__ BTh,
                                __hip_bfloat16* __restrict__ BTl, int K, int N, int Kp) {
    __shared__ float tile[32][33];
    int k0 = blockIdx.x * 32, n0 = blockIdx.y * 32;
    int tx = threadIdx.x, ty = threadIdx.y;
    #pragma unroll
    for (int j = 0; j < 32; j += 8) {
        int k = k0 + ty + j;
        tile[ty + j][tx] = (k < K) ? W[(size_t)k * N + n0 + tx] : 0.f;
    }
    __syncthreads();
    #pragma unroll
    for (int j = 0; j < 32; j += 8) {
        int n = n0 + ty + j;
        int k = k0 + tx;
        float v = tile[tx][ty + j];
        __hip_bfloat16 hi = __float2bfloat16(v);
        float r = v - __bfloat162float(hi);
        BTh[(size_t)n * Kp + k] = hi;
        BTl[(size_t)n * Kp + k] = __float2bfloat16(r);
    }
}

// ---------------- split-bf16 MFMA GEMM + fused attention dots ----------------
// C[M][1024] = (Ah+Al) @ (BTh+BTl)^T via expanded K: [Ah|Al|Ah] x [BTh|BTh|BTl]
// 128x128 tile, 4 waves, 4x4 frags of mfma_f32_16x16x32_bf16, BK=64.
// LDS: linear dest for global_load_lds; XOR swizzle (row&7)<<4 on the GLOBAL
// source address when staging and on the ds_read byte offset (rule #21).
// Epilogue additionally accumulates hs[m] += sum_n C[m][n]*asrc[n] and
// hd[m] += sum_n C[m][n]*adst[n] via 16-lane shfl reduce + atomicAdd.
// Block remap: bijective XCD-chunked swizzle (nwg = 632 = 8*79, %8 == 0),
// N-block fastest within an XCD so the 8 N-blocks sharing an A-panel hit
// the same XCD L2.

__global__ __launch_bounds__(256) void gemm_split_mfma(
        const __hip_bfloat16* __restrict__ Ah, const __hip_bfloat16* __restrict__ Al,
        const __hip_bfloat16* __restrict__ BTh, const __hip_bfloat16* __restrict__ BTl,
        float* __restrict__ C, const float* __restrict__ asrc,
        const float* __restrict__ adst, float* __restrict__ hs,
        float* __restrict__ hd, int Mreal, int Kp) {
    __shared__ char As[128 * 128];   // 128 rows x 64 bf16 (128B per row)
    __shared__ char Bs[128 * 128];
    const int t    = threadIdx.x;
    const int lane = t & 63;
    const int wid  = t >> 6;
    // XCD-chunked bijective remap of the 1D grid (632 blocks = 79 M x 8 N)
    const int chunk = (int)gridDim.x >> 3;          // 79
    const int vid  = ((int)blockIdx.x & 7) * chunk + ((int)blockIdx.x >> 3);
    const int n0 = (vid & 7) * 128;
    const int m0 = (vid >> 3) * 128;
    const int wr = (wid >> 1) * 64;
    const int wc = (wid & 1) * 64;
    const int fr = lane & 15;        // frag row (m or n) within 16
    const int kg = lane >> 4;        // k-group 0..3
    const int swz = (fr & 7) << 4;   // read-side swizzle
    const int Keff = 3 * Kp;

    // staging geometry: chunk16 = i*256 + t; LDS dest byte = chunk16*16 (linear)
    const int rbase = t >> 3;                                   // row within 32-row group
    const int srcb  = ((t & 7) << 4) ^ (((t >> 3) & 7) << 4);   // pre-swizzled src byte
    const int scol  = srcb >> 1;                                // src element offset in [0,64)

    f32x4 acc[4][4] = {};

    for (int k0 = 0; k0 < Keff; k0 += 64) {
        const int seg = (k0 >= Kp) + (k0 >= 2 * Kp);   // 0,1,2
        const int kb  = k0 - seg * Kp;
        const __hip_bfloat16* SA = (seg == 1) ? Al  : Ah;
        const __hip_bfloat16* SB = (seg == 2) ? BTl : BTh;
        #pragma unroll
        for (int i = 0; i < 4; ++i) {
            int row = i * 32 + rbase;
            const __hip_bfloat16* ga = SA + (size_t)(m0 + row) * Kp + kb + scol;
            const __hip_bfloat16* gb = SB + (size_t)(n0 + row) * Kp + kb + scol;
            GLOAD_LDS16(ga, As + (i * 256 + wid * 64) * 16);
            GLOAD_LDS16(gb, Bs + (i * 256 + wid * 64) * 16);
        }
        __syncthreads();
        #pragma unroll
        for (int kk = 0; kk < 2; ++kk) {
            const int ko = (kk * 64 + kg * 16) ^ swz;
            bf16x8 af[4], bfr[4];
            #pragma unroll
            for (int f = 0; f < 4; ++f) {
                af[f]  = *(const bf16x8*)(As + (wr + f * 16 + fr) * 128 + ko);
                bfr[f] = *(const bf16x8*)(Bs + (wc + f * 16 + fr) * 128 + ko);
            }
            #pragma unroll
            for (int fm = 0; fm < 4; ++fm)
                #pragma unroll
                for (int fn = 0; fn < 4; ++fn)
                    acc[fm][fn] = __builtin_amdgcn_mfma_f32_16x16x32_bf16(
                        af[fm], bfr[fn], acc[fm][fn], 0, 0, 0);
        }
        __syncthreads();
    }

    // epilogue: C/D layout col=lane&15, row=(lane>>4)*4+j
    #pragma unroll
    for (int fm = 0; fm < 4; ++fm) {
        int mb = m0 + wr + fm * 16 + kg * 4;
        #pragma unroll
        for (int fn = 0; fn < 4; ++fn) {
            int cn = n0 + wc + fn * 16 + fr;
            #pragma unroll
            for (int j = 0; j < 4; ++j) {
                int m = mb + j;
                if (m < Mreal) C[(size_t)m * 1024 + cn] = acc[fm][fn][j];
            }
        }
    }

    // fused attention dots: hs[m] += sum_cols C[m][col]*asrc[col] (this block's cols)
    float av[4], dv[4];
    #pragma unroll
    for (int fn = 0; fn < 4; ++fn) {
        int cn = n0 + wc + fn * 16 + fr;
        av[fn] = asrc[cn];
        dv[fn] = adst[cn];
    }
    #pragma unroll
    for (int fm = 0; fm < 4; ++fm) {
        #pragma unroll
        for (int j = 0; j < 4; ++j) {
            float v1 = acc[fm][0][j] * av[0] + acc[fm][1][j] * av[1]
                     + acc[fm][2][j] * av[2] + acc[fm][3][j] * av[3];
            float v2 = acc[fm][0][j] * dv[0] + acc[fm][1][j] * dv[1]
                     + acc[fm][2][j] * dv[2] + acc[fm][3][j] * dv[3];
            #pragma unroll
            for (int o = 1; o < 16; o <<= 1) {
                v1 += __shfl_xor(v1, o);
                v2 += __shfl_xor(v2, o);
            }
            int m = m0 + wr + fm * 16 + kg * 4 + j;
            if (fr == 0 && m < Mreal) {
                atomicAdd(&hs[m], v1);
                atomicAdd(&hd[m], v2);
            }
        }
    }
}

// ---------------- per-dst softmax + weighted aggregation ----------------
// mode 0: write fp32 out;  mode 1: write hi/lo bf16 split (layer-2 GEMM A operand)

__global__ __launch_bounds__(256) void gat_aggregate(
        const float* __restrict__ h, const float* __restrict__ hs,
        const float* __restrict__ hd, const int* __restrict__ offs,
        const int* __restrict__ ssrc, float* __restrict__ sscore,
        const float* __restrict__ bias, float* __restrict__ outf,
        __hip_bfloat16* __restrict__ outh, __hip_bfloat16* __restrict__ outl,
        int mode) {
    int i = blockIdx.x;
    int t = threadIdx.x;
    int lane = t & 63;
    int start = offs[i], end = offs[i + 1];
    __shared__ float s_inv_denom;

    if (t < 64) {
        float hdi  = hd[i];
        float lmax = -INFINITY;
        for (int p = start + lane; p < end; p += 64) {
            float s = hs[ssrc[p]] + hdi;
            s = (s >= 0.f) ? s : s * NEG_SLOPE;
            sscore[p] = s;
            lmax = fmaxf(lmax, s);
        }
        #pragma unroll
        for (int o = 32; o; o >>= 1) lmax = fmaxf(lmax, __shfl_xor(lmax, o));
        float lsum = 0.f;
        for (int p = start + lane; p < end; p += 64) {
            float ex = __expf(sscore[p] - lmax);
            sscore[p] = ex;
            lsum += ex;
        }
        #pragma unroll
        for (int o = 32; o; o >>= 1) lsum += __shfl_xor(lsum, o);
        if (lane == 0) s_inv_denom = 1.0f / lsum;
    }
    __syncthreads();
    float inv = s_inv_denom;

    int c = t * 4;
    float4 acc = {0.f, 0.f, 0.f, 0.f};
    for (int p = start; p < end; ++p) {
        float a  = sscore[p];
        int   sj = ssrc[p];
        float4 hv = *(const float4*)(h + (size_t)sj * D + c);
        acc.x += a * hv.x; acc.y += a * hv.y; acc.z += a * hv.z; acc.w += a * hv.w;
    }
    float4 b4 = *(const float4*)(bias + c);
    float4 r;
    r.x = fmaxf(acc.x * inv + b4.x, 0.f);   // ReLU (both layers)
    r.y = fmaxf(acc.y * inv + b4.y, 0.f);
    r.z = fmaxf(acc.z * inv + b4.z, 0.f);
    r.w = fmaxf(acc.w * inv + b4.w, 0.f);

    if (mode == 0) {
        *(float4*)(outf + (size_t)i * D + c) = r;
    } else {
        __hip_bfloat16 hi4[4], lo4[4];
        float rv[4] = {r.x, r.y, r.z, r.w};
        #pragma unroll
        for (int q = 0; q < 4; ++q) {
            __hip_bfloat16 hi = __float2bfloat16(rv[q]);
            hi4[q] = hi;
            lo4[q] = __float2bfloat16(rv[q] - __bfloat162float(hi));
        }
        *(float2*)(outh + (size_t)i * D + c) = *(float2*)hi4;
        *(float2*)(outl + (size_t)i * D + c) = *(float2*)lo4;
    }
}

// ---------------- final fc + softmax ----------------

__global__ void fc_softmax(const float* __restrict__ emb, const float* __restrict__ fcw,
                           const float* __restrict__ fcb, float* __restrict__ out) {
    int wid  = (int)((blockIdx.x * blockDim.x + threadIdx.x) >> 6);
    int lane = threadIdx.x & 63;
    if (wid >= N_NODES) return;
    float acc[N_CLS] = {};
    const float* row = emb + (size_t)wid * D;
    for (int k = lane; k < D; k += 64) {
        float v = row[k];
        #pragma unroll
        for (int c = 0; c < N_CLS; ++c) acc[c] += v * fcw[k * N_CLS + c];
    }
    #pragma unroll
    for (int c = 0; c < N_CLS; ++c) {
        #pragma unroll
        for (int o = 32; o; o >>= 1) acc[c] += __shfl_xor(acc[c], o);
    }
    if (lane == 0) {
        float logit[N_CLS];
        float m = -INFINITY;
        #pragma unroll
        for (int c = 0; c < N_CLS; ++c) { logit[c] = acc[c] + fcb[c]; m = fmaxf(m, logit[c]); }
        float s = 0.f;
        #pragma unroll
        for (int c = 0; c < N_CLS; ++c) { logit[c] = __expf(logit[c] - m); s += logit[c]; }
        float invs = 1.0f / s;
        #pragma unroll
        for (int c = 0; c < N_CLS; ++c) out[(size_t)wid * N_CLS + c] = logit[c] * invs;
    }
}

// ---------------- launch ----------------

extern "C" void kernel_launch(void* const* d_in, const int* in_sizes, int n_in,
                              void* d_out, int out_size, void* d_ws, size_t ws_size,
                              hipStream_t stream) {
    const float* x        = (const float*)d_in[0];
    const int*   ei       = (const int*)d_in[1];
    const float* W1       = (const float*)d_in[2];
    const float* att_src1 = (const float*)d_in[3];
    const float* att_dst1 = (const float*)d_in[4];
    const float* b1       = (const float*)d_in[5];
    const float* W2       = (const float*)d_in[6];
    const float* att_src2 = (const float*)d_in[7];
    const float* att_dst2 = (const float*)d_in[8];
    const float* b2       = (const float*)d_in[9];
    const float* fc_w     = (const float*)d_in[10];
    const float* fc_b     = (const float*)d_in[11];
    float* out = (float*)d_out;

    const int* src = ei;
    const int* dst = ei + N_EDGES;

    char* w = (char*)d_ws;
    #define ALLOC(name, bytes) char* name = w; w += (((size_t)(bytes) + 255) & ~(size_t)255)
    ALLOC(p_h,     (size_t)N_NODES * D * 4);
    ALLOC(p_emb,   (size_t)N_NODES * D * 4);
    ALLOC(p_score, (size_t)E_TOT * 4);
    ALLOC(p_hs,    (size_t)N_NODES * 4);
    ALLOC(p_hd,    (size_t)N_NODES * 4);
    ALLOC(p_deg,   (size_t)N_NODES * 4);
    ALLOC(p_offs,  (size_t)(N_NODES + 1) * 4);
    ALLOC(p_pos,   (size_t)N_NODES * 4);
    ALLOC(p_ssrc,  (size_t)E_TOT * 4);
    // A-split region shared by layer 1 and layer 2 (gemm1 finishes before aggregate-1 writes)
    ALLOC(p_asplit, (size_t)2 * MP * KP2 * 2);
    ALLOC(p_bt1h,  (size_t)D * KP1 * 2);
    ALLOC(p_bt1l,  (size_t)D * KP1 * 2);
    ALLOC(p_bt2h,  (size_t)D * KP2 * 2);
    ALLOC(p_bt2l,  (size_t)D * KP2 * 2);
    #undef ALLOC

    float* h      = (float*)p_h;
    float* emb    = (float*)p_emb;
    float* sscore = (float*)p_score;
    float* hs     = (float*)p_hs;
    float* hd     = (float*)p_hd;
    int*   deg    = (int*)p_deg;
    int*   offs   = (int*)p_offs;
    int*   pos    = (int*)p_pos;
    int*   ssrc   = (int*)p_ssrc;
    __hip_bfloat16* Ah1  = (__hip_bfloat16*)p_asplit;
    __hip_bfloat16* Al1  = Ah1 + (size_t)MP * KP1;
    __hip_bfloat16* Ah2  = (__hip_bfloat16*)p_asplit;
    __hip_bfloat16* Al2  = Ah2 + (size_t)MP * KP2;
    __hip_bfloat16* BT1h = (__hip_bfloat16*)p_bt1h;
    __hip_bfloat16* BT1l = (__hip_bfloat16*)p_bt1l;
    __hip_bfloat16* BT2h = (__hip_bfloat16*)p_bt2h;
    __hip_bfloat16* BT2l = (__hip_bfloat16*)p_bt2l;

    // CSR build
    init_deg<<<(N_NODES + 255) / 256, 256, 0, stream>>>(deg);
    count_edges<<<(N_EDGES + 255) / 256, 256, 0, stream>>>(dst, deg);
    scan_offs<<<1, 1024, 0, stream>>>(deg, offs, pos);
    scatter_edges<<<(E_TOT + 255) / 256, 256, 0, stream>>>(src, dst, pos, ssrc);

    // weight transpose+split + pad-row zero for layer-2 A (disjoint from layer-1 A region)
    dim3 tb(32, 8);
    transpose_split<<<dim3(KP1 / 32, D / 32), tb, 0, stream>>>(W1, BT1h, BT1l, F_IN, D, KP1);
    transpose_split<<<dim3(KP2 / 32, D / 32), tb, 0, stream>>>(W2, BT2h, BT2l, D, D, KP2);
    zero_pad_rows<<<((MP - N_NODES) * KP2 + 255) / 256, 256, 0, stream>>>(Ah2, Al2);

    const int gemmGrid = (D / 128) * (MP / 128);   // 632 = 8*79, %8 == 0 (bijective swizzle ok)

    // layer 1: h = x @ W1 (split-bf16 MFMA, fused att1 dots)
    split_rows<<<((size_t)MP * KP1 + 255) / 256, 256, 0, stream>>>(x, Ah1, Al1, N_NODES, F_IN, MP, KP1);
    zero2<<<(N_NODES + 255) / 256, 256, 0, stream>>>(hs, hd, N_NODES);
    gemm_split_mfma<<<gemmGrid, 256, 0, stream>>>(Ah1, Al1, BT1h, BT1l, h,
                                                  att_src1, att_dst1, hs, hd, N_NODES, KP1);
    gat_aggregate<<<N_NODES, 256, 0, stream>>>(h, hs, hd, offs, ssrc, sscore, b1,
                                               (float*)nullptr, Ah2, Al2, 1);

    // layer 2: h = emb @ W2 (A operand already split by aggregate-1)
    zero2<<<(N_NODES + 255) / 256, 256, 0, stream>>>(hs, hd, N_NODES);
    gemm_split_mfma<<<gemmGrid, 256, 0, stream>>>(Ah2, Al2, BT2h, BT2l, h,
                                                  att_src2, att_dst2, hs, hd, N_NODES, KP2);
    gat_aggregate<<<N_NODES, 256, 0, stream>>>(h, hs, hd, offs, ssrc, sscore, b2,
                                               emb, (__hip_bfloat16*)nullptr,
                                               (__hip_bfloat16*)nullptr, 0);

    // classifier
    fc_softmax<<<(N_NODES * 64 + 255) / 256, 256, 0, stream>>>(emb, fc_w, fc_b, out);
}

// Round 5
// 472.116 us; speedup vs baseline: 1.8133x; 1.1361x over previous
//
#include <hip/hip_runtime.h>
#include <hip/hip_bf16.h>
#include <math.h>

#define N_NODES 10000
#define N_EDGES 160000
#define E_TOT   (N_EDGES + N_NODES)
#define F_IN    300
#define D       1024
#define N_CLS   10
#define NEG_SLOPE 0.2f

#define MP      10112              // 79 * 128, padded M
#define KP1     320                // F_IN padded to mult of 32
#define KP2     1024

typedef __attribute__((ext_vector_type(8))) short bf16x8;
typedef __attribute__((ext_vector_type(4))) float f32x4;

#define GLOAD_LDS16(g, l) __builtin_amdgcn_global_load_lds( \
    (const __attribute__((address_space(1))) void*)(g), \
    (__attribute__((address_space(3))) void*)(l), 16, 0, 0)

// ---------------- CSR build ----------------

__global__ void init_deg(int* __restrict__ deg) {
    int i = blockIdx.x * blockDim.x + threadIdx.x;
    if (i < N_NODES) deg[i] = 1;  // self loop contributes 1
}

__global__ void count_edges(const int* __restrict__ dst, int* __restrict__ deg) {
    int e = blockIdx.x * blockDim.x + threadIdx.x;
    if (e < N_EDGES) atomicAdd(&deg[dst[e]], 1);
}

__global__ void scan_offs(const int* __restrict__ deg, int* __restrict__ offs,
                          int* __restrict__ pos) {
    __shared__ int sbuf[1024];
    __shared__ int scarry;
    int t = threadIdx.x;
    if (t == 0) { scarry = 0; offs[0] = 0; }
    __syncthreads();
    for (int base = 0; base < N_NODES; base += 1024) {
        int v = (base + t < N_NODES) ? deg[base + t] : 0;
        sbuf[t] = v;
        __syncthreads();
        for (int off = 1; off < 1024; off <<= 1) {
            int add = (t >= off) ? sbuf[t - off] : 0;
            __syncthreads();
            sbuf[t] += add;
            __syncthreads();
        }
        int carry = scarry;
        if (base + t < N_NODES) {
            int incl = carry + sbuf[t];
            offs[base + t + 1] = incl;
            pos[base + t]      = incl - v;
        }
        __syncthreads();
        if (t == 1023) scarry = carry + sbuf[1023];
        __syncthreads();
    }
}

__global__ void scatter_edges(const int* __restrict__ src, const int* __restrict__ dst,
                              int* __restrict__ pos, int* __restrict__ ssrc) {
    int e = blockIdx.x * blockDim.x + threadIdx.x;
    if (e < N_EDGES) {
        int d = dst[e];
        int p = atomicAdd(&pos[d], 1);
        ssrc[p] = src[e];
    } else if (e < E_TOT) {
        int i = e - N_EDGES;
        int p = atomicAdd(&pos[i], 1);
        ssrc[p] = i;
    }
}

// ---------------- small utility kernels ----------------

__global__ void zero2(float* __restrict__ a, float* __restrict__ b, int n) {
    int i = blockIdx.x * blockDim.x + threadIdx.x;
    if (i < n) { a[i] = 0.f; b[i] = 0.f; }
}

__global__ void zero_pad_rows(__hip_bfloat16* __restrict__ Ah, __hip_bfloat16* __restrict__ Al) {
    int idx = blockIdx.x * blockDim.x + threadIdx.x;
    const int total = (MP - N_NODES) * KP2;
    if (idx < total) {
        __hip_bfloat16 z = __float2bfloat16(0.f);
        Ah[(size_t)N_NODES * KP2 + idx] = z;
        Al[(size_t)N_NODES * KP2 + idx] = z;
    }
}

// ---------------- hi/lo bf16 split of row-major A [M][K] -> [Mp][Kp] ----------------

__global__ void split_rows(const float* __restrict__ A, __hip_bfloat16* __restrict__ Ah,
                           __hip_bfloat16* __restrict__ Al, int M, int K, int Mp, int Kp) {
    int idx = blockIdx.x * blockDim.x + threadIdx.x;
    if (idx >= Mp * Kp) return;
    int m = idx / Kp, k = idx - m * Kp;
    float v = (m < M && k < K) ? A[(size_t)m * K + k] : 0.f;
    __hip_bfloat16 hi = __float2bfloat16(v);
    float r = v - __bfloat162float(hi);
    Ah[idx] = hi;
    Al[idx] = __float2bfloat16(r);
}

// ---------------- transpose + hi/lo split of W [K][N] -> BT [N][Kp] ----------------

__global__ void transpose_split(const float* __restrict__ W, __hip_bfloat16* __restrict__ BTh,
                                __hip_bfloat16* __restrict__ BTl, int K, int N, int Kp) {
    __shared__ float tile[32][33];
    int k0 = blockIdx.x * 32, n0 = blockIdx.y * 32;
    int tx = threadIdx.x, ty = threadIdx.y;
    #pragma unroll
    for (int j = 0; j < 32; j += 8) {
        int k = k0 + ty + j;
        tile[ty + j][tx] = (k < K) ? W[(size_t)k * N + n0 + tx] : 0.f;
    }
    __syncthreads();
    #pragma unroll
    for (int j = 0; j < 32; j += 8) {
        int n = n0 + ty + j;
        int k = k0 + tx;
        float v = tile[tx][ty + j];
        __hip_bfloat16 hi = __float2bfloat16(v);
        float r = v - __bfloat162float(hi);
        BTh[(size_t)n * Kp + k] = hi;
        BTl[(size_t)n * Kp + k] = __float2bfloat16(r);
    }
}

// ---------------- split-bf16 MFMA GEMM, combined-stage BK=32 ----------------
// Stages all 4 tiles {Ah,Al,Bh,Bl} (128 rows x 32 cols bf16 = 8KB each, 32KB LDS)
// ONCE per 32-K step and runs all 3 split terms (hh, lh, hl) -> 48 MFMA/step.
// vs previous: -33% global staging, -33% barriers, same MFMA count.
// LDS rows are 64B = 4x16B slots; slot s holds global slot s ^ ((row>>1)&3);
// reads use slot kg ^ ((fr>>1)&3) -> 2-way bank alias per 16-lane b128 phase (free).
// Epilogue: C write + fused attention dots (hs/hd atomicAdd).
// Grid: 632 blocks, bijective XCD-chunked remap (632 % 8 == 0).

__global__ __launch_bounds__(256) void gemm_split_mfma(
        const __hip_bfloat16* __restrict__ Ah, const __hip_bfloat16* __restrict__ Al,
        const __hip_bfloat16* __restrict__ BTh, const __hip_bfloat16* __restrict__ BTl,
        float* __restrict__ C, const float* __restrict__ asrc,
        const float* __restrict__ adst, float* __restrict__ hs,
        float* __restrict__ hd, int Mreal, int Kp) {
    __shared__ char lds[32768];
    char* Ah_s = lds;
    char* Al_s = lds + 8192;
    char* Bh_s = lds + 16384;
    char* Bl_s = lds + 24576;
    const int t    = threadIdx.x;
    const int lane = t & 63;
    const int wid  = t >> 6;
    const int chunkg = (int)gridDim.x >> 3;
    const int vid  = ((int)blockIdx.x & 7) * chunkg + ((int)blockIdx.x >> 3);
    const int n0 = (vid & 7) * 128;
    const int m0 = (vid >> 3) * 128;
    const int wr = (wid >> 1) * 64;
    const int wc = (wid & 1) * 64;
    const int fr = lane & 15;
    const int kg = lane >> 4;

    // staging geometry: chunks c0=t (rows 0..63), c1=t+256 (rows 64..127)
    const int r0 = t >> 2, s0 = t & 3;
    const int r1 = r0 + 64;
    const int g0 = (s0 ^ ((r0 >> 1) & 3)) << 3;   // element offset of 16B slot
    const int g1 = (s0 ^ ((r1 >> 1) & 3)) << 3;
    const size_t oA0 = (size_t)(m0 + r0) * Kp + g0;
    const size_t oA1 = (size_t)(m0 + r1) * Kp + g1;
    const size_t oB0 = (size_t)(n0 + r0) * Kp + g0;
    const size_t oB1 = (size_t)(n0 + r1) * Kp + g1;

    // loop-invariant read offsets
    const int ko = (kg ^ ((fr >> 1) & 3)) << 4;   // byte offset of 16B slot in 64B row

    f32x4 acc[4][4] = {};

    for (int kb = 0; kb < Kp; kb += 32) {
        GLOAD_LDS16(Ah  + oA0 + kb, Ah_s + t * 16);
        GLOAD_LDS16(Ah  + oA1 + kb, Ah_s + 4096 + t * 16);
        GLOAD_LDS16(Al  + oA0 + kb, Al_s + t * 16);
        GLOAD_LDS16(Al  + oA1 + kb, Al_s + 4096 + t * 16);
        GLOAD_LDS16(BTh + oB0 + kb, Bh_s + t * 16);
        GLOAD_LDS16(BTh + oB1 + kb, Bh_s + 4096 + t * 16);
        GLOAD_LDS16(BTl + oB0 + kb, Bl_s + t * 16);
        GLOAD_LDS16(BTl + oB1 + kb, Bl_s + 4096 + t * 16);
        __syncthreads();

        bf16x8 ah[4], al[4], bh[4], bl[4];
        #pragma unroll
        for (int f = 0; f < 4; ++f) {
            int ra = (wr + f * 16 + fr) * 64 + ko;
            int rb = (wc + f * 16 + fr) * 64 + ko;
            ah[f] = *(const bf16x8*)(Ah_s + ra);
            al[f] = *(const bf16x8*)(Al_s + ra);
            bh[f] = *(const bf16x8*)(Bh_s + rb);
            bl[f] = *(const bf16x8*)(Bl_s + rb);
        }
        #pragma unroll
        for (int fm = 0; fm < 4; ++fm)
            #pragma unroll
            for (int fn = 0; fn < 4; ++fn)
                acc[fm][fn] = __builtin_amdgcn_mfma_f32_16x16x32_bf16(
                    ah[fm], bh[fn], acc[fm][fn], 0, 0, 0);
        #pragma unroll
        for (int fm = 0; fm < 4; ++fm)
            #pragma unroll
            for (int fn = 0; fn < 4; ++fn)
                acc[fm][fn] = __builtin_amdgcn_mfma_f32_16x16x32_bf16(
                    al[fm], bh[fn], acc[fm][fn], 0, 0, 0);
        #pragma unroll
        for (int fm = 0; fm < 4; ++fm)
            #pragma unroll
            for (int fn = 0; fn < 4; ++fn)
                acc[fm][fn] = __builtin_amdgcn_mfma_f32_16x16x32_bf16(
                    ah[fm], bl[fn], acc[fm][fn], 0, 0, 0);
        __syncthreads();
    }

    // epilogue: C/D layout col=lane&15, row=(lane>>4)*4+j
    #pragma unroll
    for (int fm = 0; fm < 4; ++fm) {
        int mb = m0 + wr + fm * 16 + kg * 4;
        #pragma unroll
        for (int fn = 0; fn < 4; ++fn) {
            int cn = n0 + wc + fn * 16 + fr;
            #pragma unroll
            for (int j = 0; j < 4; ++j) {
                int m = mb + j;
                if (m < Mreal) C[(size_t)m * 1024 + cn] = acc[fm][fn][j];
            }
        }
    }

    // fused attention dots
    float av[4], dv[4];
    #pragma unroll
    for (int fn = 0; fn < 4; ++fn) {
        int cn = n0 + wc + fn * 16 + fr;
        av[fn] = asrc[cn];
        dv[fn] = adst[cn];
    }
    #pragma unroll
    for (int fm = 0; fm < 4; ++fm) {
        #pragma unroll
        for (int j = 0; j < 4; ++j) {
            float v1 = acc[fm][0][j] * av[0] + acc[fm][1][j] * av[1]
                     + acc[fm][2][j] * av[2] + acc[fm][3][j] * av[3];
            float v2 = acc[fm][0][j] * dv[0] + acc[fm][1][j] * dv[1]
                     + acc[fm][2][j] * dv[2] + acc[fm][3][j] * dv[3];
            #pragma unroll
            for (int o = 1; o < 16; o <<= 1) {
                v1 += __shfl_xor(v1, o);
                v2 += __shfl_xor(v2, o);
            }
            int m = m0 + wr + fm * 16 + kg * 4 + j;
            if (fr == 0 && m < Mreal) {
                atomicAdd(&hs[m], v1);
                atomicAdd(&hd[m], v2);
            }
        }
    }
}

// ---------------- per-dst softmax + weighted aggregation ----------------
// Block-wide softmax stats (no global score buffer); gather loop 4-unrolled
// with 4 independent accumulators for MLP. Weights recomputed from hs
// (L2-resident broadcast loads) identically in sum and apply phases.
// mode 0: fp32 out; mode 1: hi/lo bf16 split out (layer-2 GEMM A operand).

__global__ __launch_bounds__(256) void gat_aggregate(
        const float* __restrict__ h, const float* __restrict__ hs,
        const float* __restrict__ hd, const int* __restrict__ offs,
        const int* __restrict__ ssrc, const float* __restrict__ bias,
        float* __restrict__ outf, __hip_bfloat16* __restrict__ outh,
        __hip_bfloat16* __restrict__ outl, int mode) {
    int i = blockIdx.x;
    int t = threadIdx.x;
    int lane = t & 63;
    int wv = t >> 6;
    int start = offs[i], end = offs[i + 1];
    __shared__ float red[8];
    float hdi = hd[i];

    // phase A: block max
    float lmax = -INFINITY;
    for (int p = start + t; p < end; p += 256) {
        float s = hs[ssrc[p]] + hdi;
        s = (s >= 0.f) ? s : s * NEG_SLOPE;
        lmax = fmaxf(lmax, s);
    }
    #pragma unroll
    for (int o = 32; o; o >>= 1) lmax = fmaxf(lmax, __shfl_xor(lmax, o));
    if (lane == 0) red[wv] = lmax;
    __syncthreads();
    float m = fmaxf(fmaxf(red[0], red[1]), fmaxf(red[2], red[3]));

    // phase B: block sum of exp
    float lsum = 0.f;
    for (int p = start + t; p < end; p += 256) {
        float s = hs[ssrc[p]] + hdi;
        s = (s >= 0.f) ? s : s * NEG_SLOPE;
        lsum += __expf(s - m);
    }
    #pragma unroll
    for (int o = 32; o; o >>= 1) lsum += __shfl_xor(lsum, o);
    if (lane == 0) red[4 + wv] = lsum;
    __syncthreads();
    float inv = 1.0f / (red[4] + red[5] + red[6] + red[7]);

    // phase C: weighted gather, 4-edge unrolled
    int c = t * 4;
    float4 a0 = {0.f,0.f,0.f,0.f}, a1 = a0, a2 = a0, a3 = a0;
    int p = start;
    for (; p + 4 <= end; p += 4) {
        int j0 = ssrc[p], j1 = ssrc[p+1], j2 = ssrc[p+2], j3 = ssrc[p+3];
        float s0 = hs[j0] + hdi; s0 = (s0 >= 0.f) ? s0 : s0 * NEG_SLOPE;
        float s1 = hs[j1] + hdi; s1 = (s1 >= 0.f) ? s1 : s1 * NEG_SLOPE;
        float s2 = hs[j2] + hdi; s2 = (s2 >= 0.f) ? s2 : s2 * NEG_SLOPE;
        float s3 = hs[j3] + hdi; s3 = (s3 >= 0.f) ? s3 : s3 * NEG_SLOPE;
        float w0 = __expf(s0 - m), w1 = __expf(s1 - m);
        float w2 = __expf(s2 - m), w3 = __expf(s3 - m);
        float4 v0 = *(const float4*)(h + (size_t)j0 * D + c);
        float4 v1 = *(const float4*)(h + (size_t)j1 * D + c);
        float4 v2 = *(const float4*)(h + (size_t)j2 * D + c);
        float4 v3 = *(const float4*)(h + (size_t)j3 * D + c);
        a0.x += w0*v0.x; a0.y += w0*v0.y; a0.z += w0*v0.z; a0.w += w0*v0.w;
        a1.x += w1*v1.x; a1.y += w1*v1.y; a1.z += w1*v1.z; a1.w += w1*v1.w;
        a2.x += w2*v2.x; a2.y += w2*v2.y; a2.z += w2*v2.z; a2.w += w2*v2.w;
        a3.x += w3*v3.x; a3.y += w3*v3.y; a3.z += w3*v3.z; a3.w += w3*v3.w;
    }
    for (; p < end; ++p) {
        int j0 = ssrc[p];
        float s0 = hs[j0] + hdi; s0 = (s0 >= 0.f) ? s0 : s0 * NEG_SLOPE;
        float w0 = __expf(s0 - m);
        float4 v0 = *(const float4*)(h + (size_t)j0 * D + c);
        a0.x += w0*v0.x; a0.y += w0*v0.y; a0.z += w0*v0.z; a0.w += w0*v0.w;
    }
    float4 acc;
    acc.x = (a0.x + a1.x) + (a2.x + a3.x);
    acc.y = (a0.y + a1.y) + (a2.y + a3.y);
    acc.z = (a0.z + a1.z) + (a2.z + a3.z);
    acc.w = (a0.w + a1.w) + (a2.w + a3.w);

    float4 b4 = *(const float4*)(bias + c);
    float4 r;
    r.x = fmaxf(acc.x * inv + b4.x, 0.f);
    r.y = fmaxf(acc.y * inv + b4.y, 0.f);
    r.z = fmaxf(acc.z * inv + b4.z, 0.f);
    r.w = fmaxf(acc.w * inv + b4.w, 0.f);

    if (mode == 0) {
        *(float4*)(outf + (size_t)i * D + c) = r;
    } else {
        __hip_bfloat16 hi4[4], lo4[4];
        float rv[4] = {r.x, r.y, r.z, r.w};
        #pragma unroll
        for (int q = 0; q < 4; ++q) {
            __hip_bfloat16 hi = __float2bfloat16(rv[q]);
            hi4[q] = hi;
            lo4[q] = __float2bfloat16(rv[q] - __bfloat162float(hi));
        }
        *(float2*)(outh + (size_t)i * D + c) = *(float2*)hi4;
        *(float2*)(outl + (size_t)i * D + c) = *(float2*)lo4;
    }
}

// ---------------- final fc + softmax ----------------

__global__ void fc_softmax(const float* __restrict__ emb, const float* __restrict__ fcw,
                           const float* __restrict__ fcb, float* __restrict__ out) {
    int wid  = (int)((blockIdx.x * blockDim.x + threadIdx.x) >> 6);
    int lane = threadIdx.x & 63;
    if (wid >= N_NODES) return;
    float acc[N_CLS] = {};
    const float* row = emb + (size_t)wid * D;
    for (int k = lane * 4; k < D; k += 256) {
        float4 v = *(const float4*)(row + k);
        #pragma unroll
        for (int c = 0; c < N_CLS; ++c)
            acc[c] += v.x * fcw[k * N_CLS + c] + v.y * fcw[(k+1) * N_CLS + c]
                    + v.z * fcw[(k+2) * N_CLS + c] + v.w * fcw[(k+3) * N_CLS + c];
    }
    #pragma unroll
    for (int c = 0; c < N_CLS; ++c) {
        #pragma unroll
        for (int o = 32; o; o >>= 1) acc[c] += __shfl_xor(acc[c], o);
    }
    if (lane == 0) {
        float logit[N_CLS];
        float m = -INFINITY;
        #pragma unroll
        for (int c = 0; c < N_CLS; ++c) { logit[c] = acc[c] + fcb[c]; m = fmaxf(m, logit[c]); }
        float s = 0.f;
        #pragma unroll
        for (int c = 0; c < N_CLS; ++c) { logit[c] = __expf(logit[c] - m); s += logit[c]; }
        float invs = 1.0f / s;
        #pragma unroll
        for (int c = 0; c < N_CLS; ++c) out[(size_t)wid * N_CLS + c] = logit[c] * invs;
    }
}

// ---------------- launch ----------------

extern "C" void kernel_launch(void* const* d_in, const int* in_sizes, int n_in,
                              void* d_out, int out_size, void* d_ws, size_t ws_size,
                              hipStream_t stream) {
    const float* x        = (const float*)d_in[0];
    const int*   ei       = (const int*)d_in[1];
    const float* W1       = (const float*)d_in[2];
    const float* att_src1 = (const float*)d_in[3];
    const float* att_dst1 = (const float*)d_in[4];
    const float* b1       = (const float*)d_in[5];
    const float* W2       = (const float*)d_in[6];
    const float* att_src2 = (const float*)d_in[7];
    const float* att_dst2 = (const float*)d_in[8];
    const float* b2       = (const float*)d_in[9];
    const float* fc_w     = (const float*)d_in[10];
    const float* fc_b     = (const float*)d_in[11];
    float* out = (float*)d_out;

    const int* src = ei;
    const int* dst = ei + N_EDGES;

    char* w = (char*)d_ws;
    #define ALLOC(name, bytes) char* name = w; w += (((size_t)(bytes) + 255) & ~(size_t)255)
    ALLOC(p_h,     (size_t)N_NODES * D * 4);
    ALLOC(p_emb,   (size_t)N_NODES * D * 4);
    ALLOC(p_hs,    (size_t)N_NODES * 4);
    ALLOC(p_hd,    (size_t)N_NODES * 4);
    ALLOC(p_deg,   (size_t)N_NODES * 4);
    ALLOC(p_offs,  (size_t)(N_NODES + 1) * 4);
    ALLOC(p_pos,   (size_t)N_NODES * 4);
    ALLOC(p_ssrc,  (size_t)E_TOT * 4);
    ALLOC(p_asplit, (size_t)2 * MP * KP2 * 2);
    ALLOC(p_bt1h,  (size_t)D * KP1 * 2);
    ALLOC(p_bt1l,  (size_t)D * KP1 * 2);
    ALLOC(p_bt2h,  (size_t)D * KP2 * 2);
    ALLOC(p_bt2l,  (size_t)D * KP2 * 2);
    #undef ALLOC

    float* h      = (float*)p_h;
    float* emb    = (float*)p_emb;
    float* hs     = (float*)p_hs;
    float* hd     = (float*)p_hd;
    int*   deg    = (int*)p_deg;
    int*   offs   = (int*)p_offs;
    int*   pos    = (int*)p_pos;
    int*   ssrc   = (int*)p_ssrc;
    __hip_bfloat16* Ah1  = (__hip_bfloat16*)p_asplit;
    __hip_bfloat16* Al1  = Ah1 + (size_t)MP * KP1;
    __hip_bfloat16* Ah2  = (__hip_bfloat16*)p_asplit;
    __hip_bfloat16* Al2  = Ah2 + (size_t)MP * KP2;
    __hip_bfloat16* BT1h = (__hip_bfloat16*)p_bt1h;
    __hip_bfloat16* BT1l = (__hip_bfloat16*)p_bt1l;
    __hip_bfloat16* BT2h = (__hip_bfloat16*)p_bt2h;
    __hip_bfloat16* BT2l = (__hip_bfloat16*)p_bt2l;

    // CSR build
    init_deg<<<(N_NODES + 255) / 256, 256, 0, stream>>>(deg);
    count_edges<<<(N_EDGES + 255) / 256, 256, 0, stream>>>(dst, deg);
    scan_offs<<<1, 1024, 0, stream>>>(deg, offs, pos);
    scatter_edges<<<(E_TOT + 255) / 256, 256, 0, stream>>>(src, dst, pos, ssrc);

    // weight transpose+split + pad-row zero for layer-2 A
    dim3 tb(32, 8);
    transpose_split<<<dim3(KP1 / 32, D / 32), tb, 0, stream>>>(W1, BT1h, BT1l, F_IN, D, KP1);
    transpose_split<<<dim3(KP2 / 32, D / 32), tb, 0, stream>>>(W2, BT2h, BT2l, D, D, KP2);
    zero_pad_rows<<<((MP - N_NODES) * KP2 + 255) / 256, 256, 0, stream>>>(Ah2, Al2);

    const int gemmGrid = (D / 128) * (MP / 128);   // 632 = 8*79

    // layer 1
    split_rows<<<((size_t)MP * KP1 + 255) / 256, 256, 0, stream>>>(x, Ah1, Al1, N_NODES, F_IN, MP, KP1);
    zero2<<<(N_NODES + 255) / 256, 256, 0, stream>>>(hs, hd, N_NODES);
    gemm_split_mfma<<<gemmGrid, 256, 0, stream>>>(Ah1, Al1, BT1h, BT1l, h,
                                                  att_src1, att_dst1, hs, hd, N_NODES, KP1);
    gat_aggregate<<<N_NODES, 256, 0, stream>>>(h, hs, hd, offs, ssrc, b1,
                                               (float*)nullptr, Ah2, Al2, 1);

    // layer 2
    zero2<<<(N_NODES + 255) / 256, 256, 0, stream>>>(hs, hd, N_NODES);
    gemm_split_mfma<<<gemmGrid, 256, 0, stream>>>(Ah2, Al2, BT2h, BT2l, h,
                                                  att_src2, att_dst2, hs, hd, N_NODES, KP2);
    gat_aggregate<<<N_NODES, 256, 0, stream>>>(h, hs, hd, offs, ssrc, b2,
                                               emb, (__hip_bfloat16*)nullptr,
                                               (__hip_bfloat16*)nullptr, 0);

    // classifier
    fc_softmax<<<(N_NODES * 64 + 255) / 256, 256, 0, stream>>>(emb, fc_w, fc_b, out);
}

// Round 7
// 437.117 us; speedup vs baseline: 1.9585x; 1.0801x over previous
//
#include <hip/hip_runtime.h>
#include <hip/hip_bf16.h>
#include <math.h>

#define N_NODES 10000
#define N_EDGES 160000
#define E_TOT   (N_EDGES + N_NODES)
#define F_IN    300
#define D       1024
#define N_CLS   10
#define NEG_SLOPE 0.2f

#define MP      10112              // 79 * 128, padded M
#define KP1     320                // F_IN padded to mult of 32
#define KP2     1024

typedef __attribute__((ext_vector_type(8))) short bf16x8;
typedef __attribute__((ext_vector_type(4))) float f32x4;

#define GLOAD_LDS16(g, l) __builtin_amdgcn_global_load_lds( \
    (const __attribute__((address_space(1))) void*)(g), \
    (__attribute__((address_space(3))) void*)(l), 16, 0, 0)

// ---------------- CSR build ----------------

__global__ void init_deg(int* __restrict__ deg) {
    int i = blockIdx.x * blockDim.x + threadIdx.x;
    if (i < N_NODES) deg[i] = 1;  // self loop
}

__global__ void count_edges(const int* __restrict__ dst, int* __restrict__ deg) {
    int e = blockIdx.x * blockDim.x + threadIdx.x;
    if (e < N_EDGES) atomicAdd(&deg[dst[e]], 1);
}

__global__ void scan_offs(const int* __restrict__ deg, int* __restrict__ offs,
                          int* __restrict__ pos) {
    __shared__ int sbuf[1024];
    __shared__ int scarry;
    int t = threadIdx.x;
    if (t == 0) { scarry = 0; offs[0] = 0; }
    __syncthreads();
    for (int base = 0; base < N_NODES; base += 1024) {
        int v = (base + t < N_NODES) ? deg[base + t] : 0;
        sbuf[t] = v;
        __syncthreads();
        for (int off = 1; off < 1024; off <<= 1) {
            int add = (t >= off) ? sbuf[t - off] : 0;
            __syncthreads();
            sbuf[t] += add;
            __syncthreads();
        }
        int carry = scarry;
        if (base + t < N_NODES) {
            int incl = carry + sbuf[t];
            offs[base + t + 1] = incl;
            pos[base + t]      = incl - v;
        }
        __syncthreads();
        if (t == 1023) scarry = carry + sbuf[1023];
        __syncthreads();
    }
}

__global__ void scatter_edges(const int* __restrict__ src, const int* __restrict__ dst,
                              int* __restrict__ pos, int* __restrict__ ssrc) {
    int e = blockIdx.x * blockDim.x + threadIdx.x;
    if (e < N_EDGES) {
        int d = dst[e];
        int p = atomicAdd(&pos[d], 1);
        ssrc[p] = src[e];
    } else if (e < E_TOT) {
        int i = e - N_EDGES;
        int p = atomicAdd(&pos[i], 1);
        ssrc[p] = i;
    }
}

// ---------------- projected attention vectors: u = W @ a_src, v = W @ a_dst ----------------

__global__ void prep_uv(const float* __restrict__ W1, const float* __restrict__ as1,
                        const float* __restrict__ ad1, const float* __restrict__ W2,
                        const float* __restrict__ as2, const float* __restrict__ ad2,
                        float* __restrict__ u1, float* __restrict__ v1,
                        float* __restrict__ u2, float* __restrict__ v2) {
    int wid  = (int)((blockIdx.x * blockDim.x + threadIdx.x) >> 6);
    int lane = threadIdx.x & 63;
    const float* row;
    const float* a;
    const float* b;
    float *du, *dv;
    int k;
    if (wid < F_IN) {
        k = wid; row = W1 + (size_t)k * D; a = as1; b = ad1; du = u1; dv = v1;
    } else if (wid < F_IN + D) {
        k = wid - F_IN; row = W2 + (size_t)k * D; a = as2; b = ad2; du = u2; dv = v2;
    } else return;
    float s1 = 0.f, s2 = 0.f;
    for (int n = lane; n < D; n += 64) {
        float w = row[n];
        s1 += w * a[n];
        s2 += w * b[n];
    }
    #pragma unroll
    for (int o = 32; o; o >>= 1) { s1 += __shfl_xor(s1, o); s2 += __shfl_xor(s2, o); }
    if (lane == 0) { du[k] = s1; dv[k] = s2; }
}

// ---------------- layer-1 node scores: hs1[i] = x_i . u1, hd1[i] = x_i . v1 ----------------

__global__ void node_scores_x(const float* __restrict__ x, const float* __restrict__ u1,
                              const float* __restrict__ v1, float* __restrict__ hs,
                              float* __restrict__ hd) {
    int wid  = (int)((blockIdx.x * blockDim.x + threadIdx.x) >> 6);
    int lane = threadIdx.x & 63;
    if (wid >= N_NODES) return;
    const float* row = x + (size_t)wid * F_IN;
    float s1 = 0.f, s2 = 0.f;
    for (int k = lane; k < F_IN; k += 64) {
        float v = row[k];
        s1 += v * u1[k];
        s2 += v * v1[k];
    }
    #pragma unroll
    for (int o = 32; o; o >>= 1) { s1 += __shfl_xor(s1, o); s2 += __shfl_xor(s2, o); }
    if (lane == 0) { hs[wid] = s1; hd[wid] = s2; }
}

// ---------------- zero hs2/hd2 + pad regions of the A-split buffers ----------------

#define ZR1 (112 * KP1)        // asplit1 pad rows, per buffer
#define ZR2 (N_NODES * 20)     // asplit1 pad cols (300..319), per buffer
#define ZR3 (112 * KP2)        // asplit2 pad rows, per buffer
#define ZTOT (2*ZR1 + 2*ZR2 + 2*ZR3 + 2*N_NODES)

__global__ void zero_misc(float* __restrict__ hs2, float* __restrict__ hd2,
                          __hip_bfloat16* __restrict__ Ah1, __hip_bfloat16* __restrict__ Al1,
                          __hip_bfloat16* __restrict__ Ah2, __hip_bfloat16* __restrict__ Al2) {
    int idx = blockIdx.x * blockDim.x + threadIdx.x;
    if (idx >= ZTOT) return;
    unsigned short z = 0;
    if (idx < 2 * ZR1) {
        __hip_bfloat16* B = (idx < ZR1) ? Ah1 : Al1;
        int off = (idx < ZR1) ? idx : idx - ZR1;
        ((unsigned short*)B)[(size_t)N_NODES * KP1 + off] = z;
    } else if ((idx -= 2 * ZR1) < 2 * ZR2) {
        __hip_bfloat16* B = (idx < ZR2) ? Ah1 : Al1;
        int off = (idx < ZR2) ? idx : idx - ZR2;
        int r = off / 20, c = 300 + off % 20;
        ((unsigned short*)B)[(size_t)r * KP1 + c] = z;
    } else if ((idx -= 2 * ZR2) < 2 * ZR3) {
        __hip_bfloat16* B = (idx < ZR3) ? Ah2 : Al2;
        int off = (idx < ZR3) ? idx : idx - ZR3;
        ((unsigned short*)B)[(size_t)N_NODES * KP2 + off] = z;
    } else {
        idx -= 2 * ZR3;
        if (idx < N_NODES) hs2[idx] = 0.f;
        else hd2[idx - N_NODES] = 0.f;
    }
}

// ---------------- transpose + hi/lo split of W [K][N] -> BT [N][Kp] ----------------

__global__ void transpose_split(const float* __restrict__ W, __hip_bfloat16* __restrict__ BTh,
                                __hip_bfloat16* __restrict__ BTl, int K, int N, int Kp) {
    __shared__ float tile[32][33];
    int k0 = blockIdx.x * 32, n0 = blockIdx.y * 32;
    int tx = threadIdx.x, ty = threadIdx.y;
    #pragma unroll
    for (int j = 0; j < 32; j += 8) {
        int k = k0 + ty + j;
        tile[ty + j][tx] = (k < K) ? W[(size_t)k * N + n0 + tx] : 0.f;
    }
    __syncthreads();
    #pragma unroll
    for (int j = 0; j < 32; j += 8) {
        int n = n0 + ty + j;
        int k = k0 + tx;
        float v = tile[tx][ty + j];
        __hip_bfloat16 hi = __float2bfloat16(v);
        float r = v - __bfloat162float(hi);
        BTh[(size_t)n * Kp + k] = hi;
        BTl[(size_t)n * Kp + k] = __float2bfloat16(r);
    }
}

// ---------------- layer-1 aggregate over raw x (300-wide) ----------------
// agg[i] = (1/denom) * sum_j exp(e_ij - m) * x_j ; output hi/lo bf16 split
// [MP][KP1]. 3 edge-groups x 75 lanes (75 float4 slots per row), 2-deep unroll.

__global__ __launch_bounds__(256) void aggregate_x(
        const float* __restrict__ x, const float* __restrict__ hs,
        const float* __restrict__ hd, const int* __restrict__ offs,
        const int* __restrict__ ssrc, __hip_bfloat16* __restrict__ outh,
        __hip_bfloat16* __restrict__ outl) {
    int i = blockIdx.x;
    int t = threadIdx.x;
    int lane = t & 63;
    int wv = t >> 6;
    int start = offs[i], end = offs[i + 1];
    __shared__ float red[8];
    __shared__ float part[2][75][4];
    float hdi = hd[i];

    // block max
    float lmax = -INFINITY;
    for (int p = start + t; p < end; p += 256) {
        float s = hs[ssrc[p]] + hdi;
        s = (s >= 0.f) ? s : s * NEG_SLOPE;
        lmax = fmaxf(lmax, s);
    }
    #pragma unroll
    for (int o = 32; o; o >>= 1) lmax = fmaxf(lmax, __shfl_xor(lmax, o));
    if (lane == 0) red[wv] = lmax;
    __syncthreads();
    float m = fmaxf(fmaxf(red[0], red[1]), fmaxf(red[2], red[3]));

    // block sum of exp
    float lsum = 0.f;
    for (int p = start + t; p < end; p += 256) {
        float s = hs[ssrc[p]] + hdi;
        s = (s >= 0.f) ? s : s * NEG_SLOPE;
        lsum += __expf(s - m);
    }
    #pragma unroll
    for (int o = 32; o; o >>= 1) lsum += __shfl_xor(lsum, o);
    if (lane == 0) red[4 + wv] = lsum;
    __syncthreads();
    float inv = 1.0f / (red[4] + red[5] + red[6] + red[7]);

    // weighted gather over x rows, 3 groups x 75 slots
    int g = t / 75;
    int s = t - g * 75;
    int c = s * 4;
    float4 a = {0.f, 0.f, 0.f, 0.f};
    if (t < 225) {
        int p = start + g;
        for (; p + 3 < end; p += 6) {
            int j0 = ssrc[p], j1 = ssrc[p + 3];
            float s0 = hs[j0] + hdi; s0 = (s0 >= 0.f) ? s0 : s0 * NEG_SLOPE;
            float s1 = hs[j1] + hdi; s1 = (s1 >= 0.f) ? s1 : s1 * NEG_SLOPE;
            float w0 = __expf(s0 - m), w1 = __expf(s1 - m);
            float4 v0 = *(const float4*)(x + (size_t)j0 * F_IN + c);
            float4 v1 = *(const float4*)(x + (size_t)j1 * F_IN + c);
            a.x += w0 * v0.x + w1 * v1.x;
            a.y += w0 * v0.y + w1 * v1.y;
            a.z += w0 * v0.z + w1 * v1.z;
            a.w += w0 * v0.w + w1 * v1.w;
        }
        if (p < end) {
            int j0 = ssrc[p];
            float s0 = hs[j0] + hdi; s0 = (s0 >= 0.f) ? s0 : s0 * NEG_SLOPE;
            float w0 = __expf(s0 - m);
            float4 v0 = *(const float4*)(x + (size_t)j0 * F_IN + c);
            a.x += w0 * v0.x; a.y += w0 * v0.y; a.z += w0 * v0.z; a.w += w0 * v0.w;
        }
    }
    if (t < 225 && g > 0) {
        part[g - 1][s][0] = a.x; part[g - 1][s][1] = a.y;
        part[g - 1][s][2] = a.z; part[g - 1][s][3] = a.w;
    }
    __syncthreads();
    if (t < 75) {
        a.x += part[0][t][0] + part[1][t][0];
        a.y += part[0][t][1] + part[1][t][1];
        a.z += part[0][t][2] + part[1][t][2];
        a.w += part[0][t][3] + part[1][t][3];
        float rv[4] = {a.x * inv, a.y * inv, a.z * inv, a.w * inv};
        __hip_bfloat16 hi4[4], lo4[4];
        #pragma unroll
        for (int q = 0; q < 4; ++q) {
            __hip_bfloat16 hi = __float2bfloat16(rv[q]);
            hi4[q] = hi;
            lo4[q] = __float2bfloat16(rv[q] - __bfloat162float(hi));
        }
        *(float2*)(outh + (size_t)i * KP1 + c) = *(float2*)hi4;
        *(float2*)(outl + (size_t)i * KP1 + c) = *(float2*)lo4;
    }
}

// ---------------- layer-2 aggregate over emb1 (1024-wide) ----------------
// output hi/lo bf16 split [MP][KP2]; no bias/relu (moved to GEMM-2 epilogue)

__global__ __launch_bounds__(256) void aggregate_d(
        const float* __restrict__ h, const float* __restrict__ hs,
        const float* __restrict__ hd, const int* __restrict__ offs,
        const int* __restrict__ ssrc, __hip_bfloat16* __restrict__ outh,
        __hip_bfloat16* __restrict__ outl) {
    int i = blockIdx.x;
    int t = threadIdx.x;
    int lane = t & 63;
    int wv = t >> 6;
    int start = offs[i], end = offs[i + 1];
    __shared__ float red[8];
    float hdi = hd[i];

    float lmax = -INFINITY;
    for (int p = start + t; p < end; p += 256) {
        float s = hs[ssrc[p]] + hdi;
        s = (s >= 0.f) ? s : s * NEG_SLOPE;
        lmax = fmaxf(lmax, s);
    }
    #pragma unroll
    for (int o = 32; o; o >>= 1) lmax = fmaxf(lmax, __shfl_xor(lmax, o));
    if (lane == 0) red[wv] = lmax;
    __syncthreads();
    float m = fmaxf(fmaxf(red[0], red[1]), fmaxf(red[2], red[3]));

    float lsum = 0.f;
    for (int p = start + t; p < end; p += 256) {
        float s = hs[ssrc[p]] + hdi;
        s = (s >= 0.f) ? s : s * NEG_SLOPE;
        lsum += __expf(s - m);
    }
    #pragma unroll
    for (int o = 32; o; o >>= 1) lsum += __shfl_xor(lsum, o);
    if (lane == 0) red[4 + wv] = lsum;
    __syncthreads();
    float inv = 1.0f / (red[4] + red[5] + red[6] + red[7]);

    int c = t * 4;
    float4 a0 = {0.f,0.f,0.f,0.f}, a1 = a0, a2 = a0, a3 = a0;
    int p = start;
    for (; p + 4 <= end; p += 4) {
        int j0 = ssrc[p], j1 = ssrc[p+1], j2 = ssrc[p+2], j3 = ssrc[p+3];
        float s0 = hs[j0] + hdi; s0 = (s0 >= 0.f) ? s0 : s0 * NEG_SLOPE;
        float s1 = hs[j1] + hdi; s1 = (s1 >= 0.f) ? s1 : s1 * NEG_SLOPE;
        float s2 = hs[j2] + hdi; s2 = (s2 >= 0.f) ? s2 : s2 * NEG_SLOPE;
        float s3 = hs[j3] + hdi; s3 = (s3 >= 0.f) ? s3 : s3 * NEG_SLOPE;
        float w0 = __expf(s0 - m), w1 = __expf(s1 - m);
        float w2 = __expf(s2 - m), w3 = __expf(s3 - m);
        float4 v0 = *(const float4*)(h + (size_t)j0 * D + c);
        float4 v1 = *(const float4*)(h + (size_t)j1 * D + c);
        float4 v2 = *(const float4*)(h + (size_t)j2 * D + c);
        float4 v3 = *(const float4*)(h + (size_t)j3 * D + c);
        a0.x += w0*v0.x; a0.y += w0*v0.y; a0.z += w0*v0.z; a0.w += w0*v0.w;
        a1.x += w1*v1.x; a1.y += w1*v1.y; a1.z += w1*v1.z; a1.w += w1*v1.w;
        a2.x += w2*v2.x; a2.y += w2*v2.y; a2.z += w2*v2.z; a2.w += w2*v2.w;
        a3.x += w3*v3.x; a3.y += w3*v3.y; a3.z += w3*v3.z; a3.w += w3*v3.w;
    }
    for (; p < end; ++p) {
        int j0 = ssrc[p];
        float s0 = hs[j0] + hdi; s0 = (s0 >= 0.f) ? s0 : s0 * NEG_SLOPE;
        float w0 = __expf(s0 - m);
        float4 v0 = *(const float4*)(h + (size_t)j0 * D + c);
        a0.x += w0*v0.x; a0.y += w0*v0.y; a0.z += w0*v0.z; a0.w += w0*v0.w;
    }
    float rv[4];
    rv[0] = ((a0.x + a1.x) + (a2.x + a3.x)) * inv;
    rv[1] = ((a0.y + a1.y) + (a2.y + a3.y)) * inv;
    rv[2] = ((a0.z + a1.z) + (a2.z + a3.z)) * inv;
    rv[3] = ((a0.w + a1.w) + (a2.w + a3.w)) * inv;
    __hip_bfloat16 hi4[4], lo4[4];
    #pragma unroll
    for (int q = 0; q < 4; ++q) {
        __hip_bfloat16 hi = __float2bfloat16(rv[q]);
        hi4[q] = hi;
        lo4[q] = __float2bfloat16(rv[q] - __bfloat162float(hi));
    }
    *(float2*)(outh + (size_t)i * KP2 + c) = *(float2*)hi4;
    *(float2*)(outl + (size_t)i * KP2 + c) = *(float2*)lo4;
}

// ---------------- split-bf16 MFMA GEMM, combined-stage BK=32 ----------------
// C = relu((Ah+Al)@(BTh+BTl)^T + bias); optional fused dots of the post-relu
// row with asrc/adst -> atomicAdd into hs/hd (next layer's attention scores).

__global__ __launch_bounds__(256) void gemm_split_mfma(
        const __hip_bfloat16* __restrict__ Ah, const __hip_bfloat16* __restrict__ Al,
        const __hip_bfloat16* __restrict__ BTh, const __hip_bfloat16* __restrict__ BTl,
        float* __restrict__ C, const float* __restrict__ bias,
        const float* __restrict__ asrc, const float* __restrict__ adst,
        float* __restrict__ hs, float* __restrict__ hd,
        int Mreal, int Kp, int dots) {
    __shared__ char lds[32768];
    char* Ah_s = lds;
    char* Al_s = lds + 8192;
    char* Bh_s = lds + 16384;
    char* Bl_s = lds + 24576;
    const int t    = threadIdx.x;
    const int lane = t & 63;
    const int wid  = t >> 6;
    const int chunkg = (int)gridDim.x >> 3;
    const int vid  = ((int)blockIdx.x & 7) * chunkg + ((int)blockIdx.x >> 3);
    const int n0 = (vid & 7) * 128;
    const int m0 = (vid >> 3) * 128;
    const int wr = (wid >> 1) * 64;
    const int wc = (wid & 1) * 64;
    const int fr = lane & 15;
    const int kg = lane >> 4;

    const int r0 = t >> 2, s0 = t & 3;
    const int r1 = r0 + 64;
    const int g0 = (s0 ^ ((r0 >> 1) & 3)) << 3;
    const int g1 = (s0 ^ ((r1 >> 1) & 3)) << 3;
    const size_t oA0 = (size_t)(m0 + r0) * Kp + g0;
    const size_t oA1 = (size_t)(m0 + r1) * Kp + g1;
    const size_t oB0 = (size_t)(n0 + r0) * Kp + g0;
    const size_t oB1 = (size_t)(n0 + r1) * Kp + g1;
    const int ko = (kg ^ ((fr >> 1) & 3)) << 4;

    f32x4 acc[4][4] = {};

    for (int kb = 0; kb < Kp; kb += 32) {
        GLOAD_LDS16(Ah  + oA0 + kb, Ah_s + t * 16);
        GLOAD_LDS16(Ah  + oA1 + kb, Ah_s + 4096 + t * 16);
        GLOAD_LDS16(Al  + oA0 + kb, Al_s + t * 16);
        GLOAD_LDS16(Al  + oA1 + kb, Al_s + 4096 + t * 16);
        GLOAD_LDS16(BTh + oB0 + kb, Bh_s + t * 16);
        GLOAD_LDS16(BTh + oB1 + kb, Bh_s + 4096 + t * 16);
        GLOAD_LDS16(BTl + oB0 + kb, Bl_s + t * 16);
        GLOAD_LDS16(BTl + oB1 + kb, Bl_s + 4096 + t * 16);
        __syncthreads();

        bf16x8 ah[4], al[4], bh[4], bl[4];
        #pragma unroll
        for (int f = 0; f < 4; ++f) {
            int ra = (wr + f * 16 + fr) * 64 + ko;
            int rb = (wc + f * 16 + fr) * 64 + ko;
            ah[f] = *(const bf16x8*)(Ah_s + ra);
            al[f] = *(const bf16x8*)(Al_s + ra);
            bh[f] = *(const bf16x8*)(Bh_s + rb);
            bl[f] = *(const bf16x8*)(Bl_s + rb);
        }
        #pragma unroll
        for (int fm = 0; fm < 4; ++fm)
            #pragma unroll
            for (int fn = 0; fn < 4; ++fn)
                acc[fm][fn] = __builtin_amdgcn_mfma_f32_16x16x32_bf16(
                    ah[fm], bh[fn], acc[fm][fn], 0, 0, 0);
        #pragma unroll
        for (int fm = 0; fm < 4; ++fm)
            #pragma unroll
            for (int fn = 0; fn < 4; ++fn)
                acc[fm][fn] = __builtin_amdgcn_mfma_f32_16x16x32_bf16(
                    al[fm], bh[fn], acc[fm][fn], 0, 0, 0);
        #pragma unroll
        for (int fm = 0; fm < 4; ++fm)
            #pragma unroll
            for (int fn = 0; fn < 4; ++fn)
                acc[fm][fn] = __builtin_amdgcn_mfma_f32_16x16x32_bf16(
                    ah[fm], bl[fn], acc[fm][fn], 0, 0, 0);
        __syncthreads();
    }

    // epilogue: bias + relu, write C; C/D layout col=lane&15, row=(lane>>4)*4+j
    float bv[4];
    #pragma unroll
    for (int fn = 0; fn < 4; ++fn) bv[fn] = bias[n0 + wc + fn * 16 + fr];
    #pragma unroll
    for (int fm = 0; fm < 4; ++fm) {
        int mb = m0 + wr + fm * 16 + kg * 4;
        #pragma unroll
        for (int fn = 0; fn < 4; ++fn) {
            int cn = n0 + wc + fn * 16 + fr;
            #pragma unroll
            for (int j = 0; j < 4; ++j) {
                float r = fmaxf(acc[fm][fn][j] + bv[fn], 0.f);
                acc[fm][fn][j] = r;
                int m = mb + j;
                if (m < Mreal) C[(size_t)m * 1024 + cn] = r;
            }
        }
    }

    if (dots) {
        float av[4], dv[4];
        #pragma unroll
        for (int fn = 0; fn < 4; ++fn) {
            int cn = n0 + wc + fn * 16 + fr;
            av[fn] = asrc[cn];
            dv[fn] = adst[cn];
        }
        #pragma unroll
        for (int fm = 0; fm < 4; ++fm) {
            #pragma unroll
            for (int j = 0; j < 4; ++j) {
                float v1 = acc[fm][0][j] * av[0] + acc[fm][1][j] * av[1]
                         + acc[fm][2][j] * av[2] + acc[fm][3][j] * av[3];
                float v2 = acc[fm][0][j] * dv[0] + acc[fm][1][j] * dv[1]
                         + acc[fm][2][j] * dv[2] + acc[fm][3][j] * dv[3];
                #pragma unroll
                for (int o = 1; o < 16; o <<= 1) {
                    v1 += __shfl_xor(v1, o);
                    v2 += __shfl_xor(v2, o);
                }
                int m = m0 + wr + fm * 16 + kg * 4 + j;
                if (fr == 0 && m < Mreal) {
                    atomicAdd(&hs[m], v1);
                    atomicAdd(&hd[m], v2);
                }
            }
        }
    }
}

// ---------------- final fc + softmax ----------------

__global__ void fc_softmax(const float* __restrict__ emb, const float* __restrict__ fcw,
                           const float* __restrict__ fcb, float* __restrict__ out) {
    int wid  = (int)((blockIdx.x * blockDim.x + threadIdx.x) >> 6);
    int lane = threadIdx.x & 63;
    if (wid >= N_NODES) return;
    float acc[N_CLS] = {};
    const float* row = emb + (size_t)wid * D;
    for (int k = lane * 4; k < D; k += 256) {
        float4 v = *(const float4*)(row + k);
        #pragma unroll
        for (int c = 0; c < N_CLS; ++c)
            acc[c] += v.x * fcw[k * N_CLS + c] + v.y * fcw[(k+1) * N_CLS + c]
                    + v.z * fcw[(k+2) * N_CLS + c] + v.w * fcw[(k+3) * N_CLS + c];
    }
    #pragma unroll
    for (int c = 0; c < N_CLS; ++c) {
        #pragma unroll
        for (int o = 32; o; o >>= 1) acc[c] += __shfl_xor(acc[c], o);
    }
    if (lane == 0) {
        float logit[N_CLS];
        float m = -INFINITY;
        #pragma unroll
        for (int c = 0; c < N_CLS; ++c) { logit[c] = acc[c] + fcb[c]; m = fmaxf(m, logit[c]); }
        float s = 0.f;
        #pragma unroll
        for (int c = 0; c < N_CLS; ++c) { logit[c] = __expf(logit[c] - m); s += logit[c]; }
        float invs = 1.0f / s;
        #pragma unroll
        for (int c = 0; c < N_CLS; ++c) out[(size_t)wid * N_CLS + c] = logit[c] * invs;
    }
}

// ---------------- launch ----------------

extern "C" void kernel_launch(void* const* d_in, const int* in_sizes, int n_in,
                              void* d_out, int out_size, void* d_ws, size_t ws_size,
                              hipStream_t stream) {
    const float* x        = (const float*)d_in[0];
    const int*   ei       = (const int*)d_in[1];
    const float* W1       = (const float*)d_in[2];
    const float* att_src1 = (const float*)d_in[3];
    const float* att_dst1 = (const float*)d_in[4];
    const float* b1       = (const float*)d_in[5];
    const float* W2       = (const float*)d_in[6];
    const float* att_src2 = (const float*)d_in[7];
    const float* att_dst2 = (const float*)d_in[8];
    const float* b2       = (const float*)d_in[9];
    const float* fc_w     = (const float*)d_in[10];
    const float* fc_b     = (const float*)d_in[11];
    float* out = (float*)d_out;

    const int* src = ei;
    const int* dst = ei + N_EDGES;

    char* w = (char*)d_ws;
    #define ALLOC(name, bytes) char* name = w; w += (((size_t)(bytes) + 255) & ~(size_t)255)
    ALLOC(p_emb,   (size_t)N_NODES * D * 4);           // emb1, later emb2 (aliased)
    ALLOC(p_hs1,   (size_t)N_NODES * 4);
    ALLOC(p_hd1,   (size_t)N_NODES * 4);
    ALLOC(p_hs2,   (size_t)N_NODES * 4);
    ALLOC(p_hd2,   (size_t)N_NODES * 4);
    ALLOC(p_deg,   (size_t)N_NODES * 4);
    ALLOC(p_offs,  (size_t)(N_NODES + 1) * 4);
    ALLOC(p_pos,   (size_t)N_NODES * 4);
    ALLOC(p_ssrc,  (size_t)E_TOT * 4);
    ALLOC(p_u1,    (size_t)F_IN * 4);
    ALLOC(p_v1,    (size_t)F_IN * 4);
    ALLOC(p_u2,    (size_t)D * 4);
    ALLOC(p_v2,    (size_t)D * 4);
    ALLOC(p_as1,   (size_t)2 * MP * KP1 * 2);          // Ah1|Al1
    ALLOC(p_as2,   (size_t)2 * MP * KP2 * 2);          // Ah2|Al2
    ALLOC(p_bt1,   (size_t)2 * D * KP1 * 2);           // BT1h|BT1l
    ALLOC(p_bt2,   (size_t)2 * D * KP2 * 2);           // BT2h|BT2l
    #undef ALLOC

    float* emb  = (float*)p_emb;
    float* hs1  = (float*)p_hs1;
    float* hd1  = (float*)p_hd1;
    float* hs2  = (float*)p_hs2;
    float* hd2  = (float*)p_hd2;
    int*   deg  = (int*)p_deg;
    int*   offs = (int*)p_offs;
    int*   pos  = (int*)p_pos;
    int*   ssrc = (int*)p_ssrc;
    float* u1 = (float*)p_u1; float* v1 = (float*)p_v1;
    float* u2 = (float*)p_u2; float* v2 = (float*)p_v2;
    __hip_bfloat16* Ah1  = (__hip_bfloat16*)p_as1;
    __hip_bfloat16* Al1  = Ah1 + (size_t)MP * KP1;
    __hip_bfloat16* Ah2  = (__hip_bfloat16*)p_as2;
    __hip_bfloat16* Al2  = Ah2 + (size_t)MP * KP2;
    __hip_bfloat16* BT1h = (__hip_bfloat16*)p_bt1;
    __hip_bfloat16* BT1l = BT1h + (size_t)D * KP1;
    __hip_bfloat16* BT2h = (__hip_bfloat16*)p_bt2;
    __hip_bfloat16* BT2l = BT2h + (size_t)D * KP2;

    // CSR build
    init_deg<<<(N_NODES + 255) / 256, 256, 0, stream>>>(deg);
    count_edges<<<(N_EDGES + 255) / 256, 256, 0, stream>>>(dst, deg);
    scan_offs<<<1, 1024, 0, stream>>>(deg, offs, pos);
    scatter_edges<<<(E_TOT + 255) / 256, 256, 0, stream>>>(src, dst, pos, ssrc);

    // projected attention vectors + weight transposes + zero pads
    prep_uv<<<((F_IN + D) * 64 + 255) / 256, 256, 0, stream>>>(
        W1, att_src1, att_dst1, W2, att_src2, att_dst2, u1, v1, u2, v2);
    dim3 tb(32, 8);
    transpose_split<<<dim3(KP1 / 32, D / 32), tb, 0, stream>>>(W1, BT1h, BT1l, F_IN, D, KP1);
    transpose_split<<<dim3(KP2 / 32, D / 32), tb, 0, stream>>>(W2, BT2h, BT2l, D, D, KP2);
    zero_misc<<<(ZTOT + 255) / 256, 256, 0, stream>>>(hs2, hd2, Ah1, Al1, Ah2, Al2);

    const int gemmGrid = (D / 128) * (MP / 128);   // 632 = 8*79

    // layer 1: scores from x.(W1 a), aggregate x, then GEMM (+b1, relu, dots for layer 2)
    node_scores_x<<<(N_NODES * 64 + 255) / 256, 256, 0, stream>>>(x, u1, v1, hs1, hd1);
    aggregate_x<<<N_NODES, 256, 0, stream>>>(x, hs1, hd1, offs, ssrc, Ah1, Al1);
    gemm_split_mfma<<<gemmGrid, 256, 0, stream>>>(Ah1, Al1, BT1h, BT1l, emb, b1,
                                                  u2, v2, hs2, hd2, N_NODES, KP1, 1);

    // layer 2: aggregate emb1, then GEMM (+b2, relu) -> emb2 (same buffer)
    aggregate_d<<<N_NODES, 256, 0, stream>>>(emb, hs2, hd2, offs, ssrc, Ah2, Al2);
    gemm_split_mfma<<<gemmGrid, 256, 0, stream>>>(Ah2, Al2, BT2h, BT2l, emb, b2,
                                                  (const float*)nullptr, (const float*)nullptr,
                                                  (float*)nullptr, (float*)nullptr,
                                                  N_NODES, KP2, 0);

    // classifier
    fc_softmax<<<(N_NODES * 64 + 255) / 256, 256, 0, stream>>>(emb, fc_w, fc_b, out);
}